// Round 2
// baseline (2200.678 us; speedup 1.0000x reference)
//
#include <hip/hip_runtime.h>
#include <hip/hip_bf16.h>

#define TB 4
#define TS 1024
#define TH 768
#define TNH 12
#define THD 64
#define TE 8
#define TKK 2
#define TF 384
#define TSF 768
#define TT (TB*TS)
#define REPS 1e-6f

// ---------------- RMSNorm: one block per token ----------------
__global__ __launch_bounds__(256) void rmsnorm_kernel(const float* __restrict__ x,
                                                      const float* __restrict__ w,
                                                      float* __restrict__ out) {
    int t = blockIdx.x;
    int tid = threadIdx.x;
    const float* xr = x + (size_t)t * TH;
    float v0 = xr[tid], v1 = xr[tid + 256], v2 = xr[tid + 512];
    float ss = v0 * v0 + v1 * v1 + v2 * v2;
    __shared__ float red[256];
    red[tid] = ss;
    __syncthreads();
    for (int s = 128; s > 0; s >>= 1) {
        if (tid < s) red[tid] += red[tid + s];
        __syncthreads();
    }
    float scale = rsqrtf(red[0] / (float)TH + REPS);
    float* o = out + (size_t)t * TH;
    o[tid]       = w[tid] * v0 * scale;
    o[tid + 256] = w[tid + 256] * v1 * scale;
    o[tid + 512] = w[tid + 512] * v2 * scale;
}

// ---------------- GEMM-BT: C[m,n] = sum_k A[m,k]*B[n,k] (+res) ----------------
// MODE 0: C = A*B^T    MODE 1: C = res + A*B^T
template <int MODE>
__global__ __launch_bounds__(256) void gemm_bt_kernel(const float* __restrict__ A,
                                                      const float* __restrict__ Bw,
                                                      const float* __restrict__ res,
                                                      float* __restrict__ C,
                                                      int M, int N, int Kc) {
    __shared__ float As[16][65];
    __shared__ float Bs[16][65];
    int tid = threadIdx.x;
    int tx = tid & 15, ty = tid >> 4;
    int m0 = blockIdx.y * 64, n0 = blockIdx.x * 64;
    int lm = tid >> 2, lk = (tid & 3) << 2;
    const float* Arow = A + (size_t)(m0 + lm) * Kc + lk;
    const float* Brow = Bw + (size_t)(n0 + lm) * Kc + lk;
    float acc[4][4] = {};
    for (int k0 = 0; k0 < Kc; k0 += 16) {
        float4 av = *(const float4*)(Arow + k0);
        float4 bv = *(const float4*)(Brow + k0);
        As[lk + 0][lm] = av.x; As[lk + 1][lm] = av.y; As[lk + 2][lm] = av.z; As[lk + 3][lm] = av.w;
        Bs[lk + 0][lm] = bv.x; Bs[lk + 1][lm] = bv.y; Bs[lk + 2][lm] = bv.z; Bs[lk + 3][lm] = bv.w;
        __syncthreads();
#pragma unroll
        for (int kk = 0; kk < 16; ++kk) {
            float a_[4], b_[4];
#pragma unroll
            for (int i = 0; i < 4; ++i) a_[i] = As[kk][ty + 16 * i];
#pragma unroll
            for (int j = 0; j < 4; ++j) b_[j] = Bs[kk][tx + 16 * j];
#pragma unroll
            for (int i = 0; i < 4; ++i)
#pragma unroll
                for (int j = 0; j < 4; ++j) acc[i][j] += a_[i] * b_[j];
        }
        __syncthreads();
    }
#pragma unroll
    for (int i = 0; i < 4; ++i) {
        int m = m0 + ty + 16 * i;
#pragma unroll
        for (int j = 0; j < 4; ++j) {
            int n = n0 + tx + 16 * j;
            float v = acc[i][j];
            if (MODE == 1) v += res[(size_t)m * N + n];
            C[(size_t)m * N + n] = v;
        }
    }
}

// ---------------- dual-B GEMM with SwiGLU epilogue (shared expert up) ----------------
__global__ __launch_bounds__(256) void gemm_dual_silu_kernel(const float* __restrict__ A,
                                                             const float* __restrict__ Bg,
                                                             const float* __restrict__ Bu,
                                                             float* __restrict__ outp,
                                                             int M, int N, int Kc) {
    __shared__ float As[16][65];
    __shared__ float Bgs[16][65];
    __shared__ float Bus[16][65];
    int tid = threadIdx.x;
    int tx = tid & 15, ty = tid >> 4;
    int m0 = blockIdx.y * 64, n0 = blockIdx.x * 64;
    int lm = tid >> 2, lk = (tid & 3) << 2;
    const float* Arow = A + (size_t)(m0 + lm) * Kc + lk;
    const float* Bgr = Bg + (size_t)(n0 + lm) * Kc + lk;
    const float* Bur = Bu + (size_t)(n0 + lm) * Kc + lk;
    float accg[4][4] = {}, accu[4][4] = {};
    for (int k0 = 0; k0 < Kc; k0 += 16) {
        float4 av = *(const float4*)(Arow + k0);
        float4 gv = *(const float4*)(Bgr + k0);
        float4 uv = *(const float4*)(Bur + k0);
        As[lk + 0][lm] = av.x; As[lk + 1][lm] = av.y; As[lk + 2][lm] = av.z; As[lk + 3][lm] = av.w;
        Bgs[lk + 0][lm] = gv.x; Bgs[lk + 1][lm] = gv.y; Bgs[lk + 2][lm] = gv.z; Bgs[lk + 3][lm] = gv.w;
        Bus[lk + 0][lm] = uv.x; Bus[lk + 1][lm] = uv.y; Bus[lk + 2][lm] = uv.z; Bus[lk + 3][lm] = uv.w;
        __syncthreads();
#pragma unroll
        for (int kk = 0; kk < 16; ++kk) {
            float a_[4], g_[4], u_[4];
#pragma unroll
            for (int i = 0; i < 4; ++i) a_[i] = As[kk][ty + 16 * i];
#pragma unroll
            for (int j = 0; j < 4; ++j) { g_[j] = Bgs[kk][tx + 16 * j]; u_[j] = Bus[kk][tx + 16 * j]; }
#pragma unroll
            for (int i = 0; i < 4; ++i)
#pragma unroll
                for (int j = 0; j < 4; ++j) { accg[i][j] += a_[i] * g_[j]; accu[i][j] += a_[i] * u_[j]; }
        }
        __syncthreads();
    }
#pragma unroll
    for (int i = 0; i < 4; ++i) {
        int m = m0 + ty + 16 * i;
#pragma unroll
        for (int j = 0; j < 4; ++j) {
            int n = n0 + tx + 16 * j;
            float g = accg[i][j], u = accu[i][j];
            float s = g / (1.f + __expf(-g));
            outp[(size_t)m * N + n] = s * u;
        }
    }
}

// ---------------- flash attention: 1 wave/block, 1 q-row/thread ----------------
__global__ __launch_bounds__(64) void attn_kernel(const float* __restrict__ q,
                                                  const float* __restrict__ k,
                                                  const float* __restrict__ v,
                                                  float* __restrict__ ctx) {
    int qt = blockIdx.x, h = blockIdx.y, b = blockIdx.z;
    int lane = threadIdx.x;
    int row = qt * 64 + lane;
    const float* qr = q + ((size_t)(b * TS + row)) * TH + h * THD;
    float qreg[64];
#pragma unroll
    for (int d4 = 0; d4 < 16; ++d4) {
        float4 t4 = *(const float4*)(qr + d4 * 4);
        qreg[d4 * 4 + 0] = t4.x; qreg[d4 * 4 + 1] = t4.y;
        qreg[d4 * 4 + 2] = t4.z; qreg[d4 * 4 + 3] = t4.w;
    }
    float O[64];
#pragma unroll
    for (int d = 0; d < 64; ++d) O[d] = 0.f;
    float mrun = -1e30f, lrun = 0.f;
    __shared__ float Ks[16][64];
    __shared__ float Vs[16][64];
    for (int j0 = 0; j0 < TS; j0 += 16) {
        int r = lane >> 2;
        int c = (lane & 3) * 16;
        const float* kr = k + ((size_t)(b * TS + j0 + r)) * TH + h * THD + c;
        const float* vr = v + ((size_t)(b * TS + j0 + r)) * TH + h * THD + c;
#pragma unroll
        for (int u4 = 0; u4 < 4; ++u4) {
            *(float4*)&Ks[r][c + u4 * 4] = *(const float4*)(kr + u4 * 4);
            *(float4*)&Vs[r][c + u4 * 4] = *(const float4*)(vr + u4 * 4);
        }
        __syncthreads();
        float s[16];
        float tmax = -1e30f;
#pragma unroll
        for (int j = 0; j < 16; ++j) {
            float acc = 0.f;
#pragma unroll
            for (int d = 0; d < 64; ++d) acc += qreg[d] * Ks[j][d];
            acc *= 0.125f;
            s[j] = acc;
            tmax = fmaxf(tmax, acc);
        }
        float mnew = fmaxf(mrun, tmax);
        float corr = __expf(mrun - mnew);
        float p[16];
        float psum = 0.f;
#pragma unroll
        for (int j = 0; j < 16; ++j) { p[j] = __expf(s[j] - mnew); psum += p[j]; }
        lrun = lrun * corr + psum;
        mrun = mnew;
#pragma unroll
        for (int d = 0; d < 64; ++d) O[d] *= corr;
#pragma unroll
        for (int j = 0; j < 16; ++j) {
            float pj = p[j];
#pragma unroll
            for (int d = 0; d < 64; ++d) O[d] += pj * Vs[j][d];
        }
        __syncthreads();
    }
    float inv = 1.f / lrun;
    float* cr = ctx + ((size_t)(b * TS + row)) * TH + h * THD;
#pragma unroll
    for (int d = 0; d < 64; ++d) cr[d] = O[d] * inv;
}

// ---------------- gate + top2 ----------------
__global__ __launch_bounds__(64) void gate_topk_kernel(const float* __restrict__ xn2,
                                                       const float* __restrict__ gate_w,
                                                       float* __restrict__ tk_w,
                                                       int* __restrict__ tk_e,
                                                       int* __restrict__ counts) {
    int t = blockIdx.x;
    int lane = threadIdx.x;
    const float* xr = xn2 + (size_t)t * TH;
    float xv[12];
#pragma unroll
    for (int i = 0; i < 12; ++i) xv[i] = xr[lane + 64 * i];
    __shared__ float logits[TE];
    for (int e = 0; e < TE; ++e) {
        const float* gw = gate_w + (size_t)e * TH;
        float acc = 0.f;
#pragma unroll
        for (int i = 0; i < 12; ++i) acc += xv[i] * gw[lane + 64 * i];
#pragma unroll
        for (int off = 32; off > 0; off >>= 1) acc += __shfl_down(acc, off);
        if (lane == 0) logits[e] = acc;
    }
    __syncthreads();
    if (lane == 0) {
        float mx = -1e30f;
        for (int e = 0; e < TE; ++e) mx = fmaxf(mx, logits[e]);
        float ex[TE];
        float sum = 0.f;
        for (int e = 0; e < TE; ++e) { ex[e] = __expf(logits[e] - mx); sum += ex[e]; }
        int e0 = 0; float p0 = -1.f;
        for (int e = 0; e < TE; ++e) if (ex[e] > p0) { p0 = ex[e]; e0 = e; }
        int e1 = -1; float p1 = -1.f;
        for (int e = 0; e < TE; ++e) if (e != e0 && ex[e] > p1) { p1 = ex[e]; e1 = e; }
        float w0 = p0 / sum, w1 = p1 / sum;
        float denom = w0 + w1 + 1e-20f;
        tk_e[2 * t] = e0; tk_e[2 * t + 1] = e1;
        tk_w[2 * t] = w0 / denom; tk_w[2 * t + 1] = w1 / denom;
        atomicAdd(&counts[e0], 1);
        atomicAdd(&counts[e1], 1);
    }
}

__global__ void scan_kernel(const int* __restrict__ counts, int* __restrict__ offsets,
                            int* __restrict__ fill) {
    if (threadIdx.x == 0) {
        int run = 0;
        for (int e = 0; e < TE; ++e) { offsets[e] = run; fill[e] = run; run += counts[e]; }
    }
}

__global__ void scatter_kernel(const int* __restrict__ tk_e, const float* __restrict__ tk_w,
                               int* __restrict__ fill, int* __restrict__ bucket_tok,
                               float* __restrict__ bucket_w, int* __restrict__ slot_of) {
    int t = blockIdx.x * blockDim.x + threadIdx.x;
    if (t >= TT) return;
    for (int kk = 0; kk < TKK; ++kk) {
        int e = tk_e[2 * t + kk];
        int pos = atomicAdd(&fill[e], 1);
        bucket_tok[pos] = t;
        bucket_w[pos] = tk_w[2 * t + kk];
        slot_of[2 * t + kk] = pos;
    }
}

// ---------------- MoE up (gathered rows, dual B, SwiGLU) ----------------
__global__ __launch_bounds__(256) void moe_gu_kernel(const float* __restrict__ xn2,
                                                     const float* __restrict__ Weg,
                                                     const float* __restrict__ Weu,
                                                     float* __restrict__ act,
                                                     const int* __restrict__ bucket_tok,
                                                     const int* __restrict__ offsets,
                                                     const int* __restrict__ counts) {
    int e = blockIdx.z;
    int ne = counts[e];
    int mbase = blockIdx.y * 64;
    if (mbase >= ne) return;
    int oe = offsets[e];
    int n0 = blockIdx.x * 64;
    __shared__ float As[16][65];
    __shared__ float Bgs[16][65];
    __shared__ float Bus[16][65];
    __shared__ int toks[64];
    int tid = threadIdx.x;
    int tx = tid & 15, ty = tid >> 4;
    if (tid < 64) {
        int r = mbase + tid;
        toks[tid] = (r < ne) ? bucket_tok[oe + r] : -1;
    }
    __syncthreads();
    int lm = tid >> 2, lk = (tid & 3) << 2;
    int tok = toks[lm];
    const float* Bgr = Weg + ((size_t)e * TF + n0 + lm) * TH + lk;
    const float* Bur = Weu + ((size_t)e * TF + n0 + lm) * TH + lk;
    float accg[4][4] = {}, accu[4][4] = {};
    for (int k0 = 0; k0 < TH; k0 += 16) {
        float4 av = make_float4(0.f, 0.f, 0.f, 0.f);
        if (tok >= 0) av = *(const float4*)(xn2 + (size_t)tok * TH + lk + k0);
        float4 gv = *(const float4*)(Bgr + k0);
        float4 uv = *(const float4*)(Bur + k0);
        As[lk + 0][lm] = av.x; As[lk + 1][lm] = av.y; As[lk + 2][lm] = av.z; As[lk + 3][lm] = av.w;
        Bgs[lk + 0][lm] = gv.x; Bgs[lk + 1][lm] = gv.y; Bgs[lk + 2][lm] = gv.z; Bgs[lk + 3][lm] = gv.w;
        Bus[lk + 0][lm] = uv.x; Bus[lk + 1][lm] = uv.y; Bus[lk + 2][lm] = uv.z; Bus[lk + 3][lm] = uv.w;
        __syncthreads();
#pragma unroll
        for (int kk = 0; kk < 16; ++kk) {
            float a_[4], g_[4], u_[4];
#pragma unroll
            for (int i = 0; i < 4; ++i) a_[i] = As[kk][ty + 16 * i];
#pragma unroll
            for (int j = 0; j < 4; ++j) { g_[j] = Bgs[kk][tx + 16 * j]; u_[j] = Bus[kk][tx + 16 * j]; }
#pragma unroll
            for (int i = 0; i < 4; ++i)
#pragma unroll
                for (int j = 0; j < 4; ++j) { accg[i][j] += a_[i] * g_[j]; accu[i][j] += a_[i] * u_[j]; }
        }
        __syncthreads();
    }
#pragma unroll
    for (int i = 0; i < 4; ++i) {
        int r = mbase + ty + 16 * i;
        if (r < ne) {
#pragma unroll
            for (int j = 0; j < 4; ++j) {
                float g = accg[i][j], u = accu[i][j];
                float s = g / (1.f + __expf(-g));
                act[(size_t)(oe + r) * TF + n0 + tx + 16 * j] = s * u;
            }
        }
    }
}

// ---------------- MoE down: yslot[slot,:] = w_slot * act[slot,:] @ Wed[e]^T ----------------
__global__ __launch_bounds__(256) void moe_down_kernel(const float* __restrict__ act,
                                                       const float* __restrict__ Wed,
                                                       float* __restrict__ yslot,
                                                       const float* __restrict__ bucket_w,
                                                       const int* __restrict__ offsets,
                                                       const int* __restrict__ counts) {
    int e = blockIdx.z;
    int ne = counts[e];
    int mbase = blockIdx.y * 64;
    if (mbase >= ne) return;
    int oe = offsets[e];
    int n0 = blockIdx.x * 64;
    __shared__ float As[16][65];
    __shared__ float Bs[16][65];
    int tid = threadIdx.x;
    int tx = tid & 15, ty = tid >> 4;
    int lm = tid >> 2, lk = (tid & 3) << 2;
    int r = mbase + lm;
    const float* Arow = act + (size_t)(oe + r) * TF + lk;
    const float* Brow = Wed + ((size_t)e * TH + n0 + lm) * TF + lk;
    float acc[4][4] = {};
    for (int k0 = 0; k0 < TF; k0 += 16) {
        float4 av = make_float4(0.f, 0.f, 0.f, 0.f);
        if (r < ne) av = *(const float4*)(Arow + k0);
        float4 bv = *(const float4*)(Brow + k0);
        As[lk + 0][lm] = av.x; As[lk + 1][lm] = av.y; As[lk + 2][lm] = av.z; As[lk + 3][lm] = av.w;
        Bs[lk + 0][lm] = bv.x; Bs[lk + 1][lm] = bv.y; Bs[lk + 2][lm] = bv.z; Bs[lk + 3][lm] = bv.w;
        __syncthreads();
#pragma unroll
        for (int kk = 0; kk < 16; ++kk) {
            float a_[4], b_[4];
#pragma unroll
            for (int i = 0; i < 4; ++i) a_[i] = As[kk][ty + 16 * i];
#pragma unroll
            for (int j = 0; j < 4; ++j) b_[j] = Bs[kk][tx + 16 * j];
#pragma unroll
            for (int i = 0; i < 4; ++i)
#pragma unroll
                for (int j = 0; j < 4; ++j) acc[i][j] += a_[i] * b_[j];
        }
        __syncthreads();
    }
#pragma unroll
    for (int i = 0; i < 4; ++i) {
        int rr = mbase + ty + 16 * i;
        if (rr < ne) {
            int slot = oe + rr;
            float wsl = bucket_w[slot];
#pragma unroll
            for (int j = 0; j < 4; ++j)
                yslot[(size_t)slot * TH + n0 + tx + 16 * j] = wsl * acc[i][j];
        }
    }
}

// ---------------- final: out = x2 + sact@Wsd^T + yslot[s0] + yslot[s1] ----------------
__global__ __launch_bounds__(256) void final_kernel(const float* __restrict__ sact,
                                                    const float* __restrict__ Wsd,
                                                    const float* __restrict__ yslot,
                                                    const int* __restrict__ slot_of,
                                                    float* __restrict__ out) {
    __shared__ float As[16][65];
    __shared__ float Bs[16][65];
    int tid = threadIdx.x;
    int tx = tid & 15, ty = tid >> 4;
    int m0 = blockIdx.y * 64, n0 = blockIdx.x * 64;
    int lm = tid >> 2, lk = (tid & 3) << 2;
    const float* Arow = sact + (size_t)(m0 + lm) * TSF + lk;
    const float* Brow = Wsd + (size_t)(n0 + lm) * TSF + lk;
    float acc[4][4] = {};
    for (int k0 = 0; k0 < TSF; k0 += 16) {
        float4 av = *(const float4*)(Arow + k0);
        float4 bv = *(const float4*)(Brow + k0);
        As[lk + 0][lm] = av.x; As[lk + 1][lm] = av.y; As[lk + 2][lm] = av.z; As[lk + 3][lm] = av.w;
        Bs[lk + 0][lm] = bv.x; Bs[lk + 1][lm] = bv.y; Bs[lk + 2][lm] = bv.z; Bs[lk + 3][lm] = bv.w;
        __syncthreads();
#pragma unroll
        for (int kk = 0; kk < 16; ++kk) {
            float a_[4], b_[4];
#pragma unroll
            for (int i = 0; i < 4; ++i) a_[i] = As[kk][ty + 16 * i];
#pragma unroll
            for (int j = 0; j < 4; ++j) b_[j] = Bs[kk][tx + 16 * j];
#pragma unroll
            for (int i = 0; i < 4; ++i)
#pragma unroll
                for (int j = 0; j < 4; ++j) acc[i][j] += a_[i] * b_[j];
        }
        __syncthreads();
    }
#pragma unroll
    for (int i = 0; i < 4; ++i) {
        int m = m0 + ty + 16 * i;
        int s0 = slot_of[2 * m], s1 = slot_of[2 * m + 1];
#pragma unroll
        for (int j = 0; j < 4; ++j) {
            int n = n0 + tx + 16 * j;
            out[(size_t)m * TH + n] = out[(size_t)m * TH + n] + acc[i][j]
                                    + yslot[(size_t)s0 * TH + n] + yslot[(size_t)s1 * TH + n];
        }
    }
}

extern "C" void kernel_launch(void* const* d_in, const int* in_sizes, int n_in,
                              void* d_out, int out_size, void* d_ws, size_t ws_size,
                              hipStream_t stream) {
    const float* hidden  = (const float*)d_in[0];
    const float* norm1_w = (const float*)d_in[1];
    const float* Wq      = (const float*)d_in[2];
    const float* Wk      = (const float*)d_in[3];
    const float* Wv      = (const float*)d_in[4];
    const float* Wo      = (const float*)d_in[5];
    const float* norm2_w = (const float*)d_in[6];
    const float* gate_w  = (const float*)d_in[7];
    const float* Weg     = (const float*)d_in[8];
    const float* Weu     = (const float*)d_in[9];
    const float* Wed     = (const float*)d_in[10];
    const float* Wsg     = (const float*)d_in[11];
    const float* Wsu     = (const float*)d_in[12];
    const float* Wsd     = (const float*)d_in[13];
    float* out = (float*)d_out;

    const size_t BUF = (size_t)TT * TH;  // 3,145,728 floats
    float* ws  = (float*)d_ws;
    float* xn1  = ws;             // buf0
    float* qb   = ws + 1 * BUF;   // buf1; later act (TT*TKK*TF == BUF)
    float* kb   = ws + 2 * BUF;   // buf2; later yslot (spans buf2+buf3)
    float* vb   = ws + 3 * BUF;   // buf3
    float* ctxb = ws + 4 * BUF;   // buf4; later sact
    float* xn2  = ws + 5 * BUF;   // buf5
    char* tail = (char*)(ws + 6 * BUF);
    int*   tk_e       = (int*)tail;
    float* tk_w       = (float*)(tail + (size_t)TT * 2 * 4);
    int*   slot_of    = (int*)(tail + (size_t)TT * 2 * 8);
    int*   bucket_tok = (int*)(tail + (size_t)TT * 2 * 12);
    float* bucket_w   = (float*)(tail + (size_t)TT * 2 * 16);
    int*   counts     = (int*)(tail + (size_t)TT * 2 * 20);
    int*   offsets    = counts + 8;
    int*   fill       = counts + 16;

    float* act   = qb;
    float* yslot = kb;
    float* sact  = ctxb;

    hipMemsetAsync(counts, 0, 8 * sizeof(int), stream);

    rmsnorm_kernel<<<TT, 256, 0, stream>>>(hidden, norm1_w, xn1);

    dim3 g768(TH / 64, TT / 64);
    gemm_bt_kernel<0><<<g768, 256, 0, stream>>>(xn1, Wq, nullptr, qb, TT, TH, TH);
    gemm_bt_kernel<0><<<g768, 256, 0, stream>>>(xn1, Wk, nullptr, kb, TT, TH, TH);
    gemm_bt_kernel<0><<<g768, 256, 0, stream>>>(xn1, Wv, nullptr, vb, TT, TH, TH);

    dim3 ga(TS / 64, TNH, TB);
    attn_kernel<<<ga, 64, 0, stream>>>(qb, kb, vb, ctxb);

    gemm_bt_kernel<1><<<g768, 256, 0, stream>>>(ctxb, Wo, hidden, out, TT, TH, TH);

    rmsnorm_kernel<<<TT, 256, 0, stream>>>(out, norm2_w, xn2);

    gate_topk_kernel<<<TT, 64, 0, stream>>>(xn2, gate_w, tk_w, tk_e, counts);
    scan_kernel<<<1, 64, 0, stream>>>(counts, offsets, fill);
    scatter_kernel<<<(TT + 255) / 256, 256, 0, stream>>>(tk_e, tk_w, fill, bucket_tok, bucket_w, slot_of);

    dim3 ggu(TF / 64, TT / 64, TE);
    moe_gu_kernel<<<ggu, 256, 0, stream>>>(xn2, Weg, Weu, act, bucket_tok, offsets, counts);
    dim3 gdn(TH / 64, TT / 64, TE);
    moe_down_kernel<<<gdn, 256, 0, stream>>>(act, Wed, yslot, bucket_w, offsets, counts);

    gemm_dual_silu_kernel<<<dim3(TSF / 64, TT / 64), 256, 0, stream>>>(xn2, Wsg, Wsu, sact, TT, TSF, TH);
    final_kernel<<<g768, 256, 0, stream>>>(sact, Wsd, yslot, slot_of, out);
}

// Round 6
// 913.212 us; speedup vs baseline: 2.4098x; 2.4098x over previous
//
#include <hip/hip_runtime.h>
#include <hip/hip_bf16.h>

#define TB 4
#define TS 1024
#define TH 768
#define TNH 12
#define THD 64
#define TE 8
#define TKK 2
#define TF 384
#define TSF 768
#define TT (TB*TS)
#define REPS 1e-6f

typedef __attribute__((ext_vector_type(8))) short short8;   // 8 bf16 = 4 VGPRs (MFMA A/B frag)
typedef __attribute__((ext_vector_type(4))) float f32x4;    // MFMA C/D frag

__device__ inline short toBF(float f) {
    __hip_bfloat16 h = __float2bfloat16(f);
    return *reinterpret_cast<short*>(&h);
}

// ---------------- RMSNorm: one block per token ----------------
__global__ __launch_bounds__(256) void rmsnorm_kernel(const float* __restrict__ x,
                                                      const float* __restrict__ w,
                                                      float* __restrict__ out) {
    int t = blockIdx.x;
    int tid = threadIdx.x;
    const float* xr = x + (size_t)t * TH;
    float v0 = xr[tid], v1 = xr[tid + 256], v2 = xr[tid + 512];
    float ss = v0 * v0 + v1 * v1 + v2 * v2;
    __shared__ float red[256];
    red[tid] = ss;
    __syncthreads();
    for (int s = 128; s > 0; s >>= 1) {
        if (tid < s) red[tid] += red[tid + s];
        __syncthreads();
    }
    float scale = rsqrtf(red[0] / (float)TH + REPS);
    float* o = out + (size_t)t * TH;
    o[tid]       = w[tid] * v0 * scale;
    o[tid + 256] = w[tid + 256] * v1 * scale;
    o[tid + 512] = w[tid + 512] * v2 * scale;
}

// ---------------- MFMA GEMM-BT: C[m,n] = sum_k A[m,k]*B[n,k], bf16 inputs, fp32 acc ----------
// EPI 0: plain store                         (QKV)
// EPI 1: + res                               (Wo + residual)
// EPI 2: expert rows, *bucket_w[slot]        (moe_down)
// EPI 3: C += acc + yslot[s0] + yslot[s1]    (final: shared-down + routed combine)
// EPI 4: dual-B, silu(g)*u                   (shared expert up)
// EPI 5: dual-B, silu(g)*u, gathered A rows  (moe_gu)
// Tile: 128(M) x BN(N) x 32(K). BN=128 single-B, 64 dual-B (VGPR budget). 4 waves,
// wave tile 64 x BN/2. Staging converts fp32->bf16 in-flight; LDS row stride 40
// shorts (80B) -> 2-way read conflict (free, m136). Fragment layout per m89:
// A/B lane holds 8 contiguous k at row lane&15, k base (lane>>4)*8; D col=lane&15,
// row=(lane>>4)*4+reg.
template <int EPI>
__global__ __launch_bounds__(256) void mfma_gemm_kernel(
    const float* __restrict__ A, const float* __restrict__ B1, const float* __restrict__ B2,
    float* __restrict__ C, const float* __restrict__ res,
    const int* __restrict__ rowmap, const int* __restrict__ offsets,
    const int* __restrict__ counts, const float* __restrict__ bucket_w,
    const float* __restrict__ yslot, const int* __restrict__ slot_of,
    int N, int K)
{
    constexpr bool DUAL = (EPI >= 4);
    constexpr bool EXPERT = (EPI == 2 || EPI == 5);
    constexpr int BN = DUAL ? 64 : 128;
    constexpr int NJ = DUAL ? 2 : 4;

    __shared__ short As[128][40];
    __shared__ short Bs1[BN][40];
    __shared__ short Bs2[DUAL ? BN : 1][40];

    int tid = threadIdx.x;
    int e = blockIdx.z;
    int ne = 0x7fffffff, oe = 0;
    if (EXPERT) { ne = counts[e]; oe = offsets[e]; }
    int mbase = blockIdx.y * 128;
    if (EXPERT && mbase >= ne) return;
    int n0 = blockIdx.x * BN;

    // ---- staging coords: thread covers row sr, k-half sh (16 fp32 each) ----
    int sr = tid >> 1;
    int sh = tid & 1;
    size_t arow = 0; bool avalid = true;
    if (EPI == 5) {
        int mrow = mbase + sr;
        int tok = (mrow < ne) ? rowmap[oe + mrow] : -1;
        avalid = tok >= 0; arow = (tok >= 0) ? (size_t)tok : 0;
    } else if (EPI == 2) {
        int mrow = mbase + sr;
        avalid = mrow < ne; arow = (size_t)(oe + mrow);
    } else {
        arow = (size_t)(mbase + sr);
    }
    const float* asrc = A + arow * K + sh * 16;
    size_t bOff = (size_t)e * (size_t)N * K;   // 0 when gridDim.z==1
    const float* b1src = B1 + bOff + (size_t)(n0 + sr) * K + sh * 16;
    const float* b2src = DUAL ? (B2 + bOff + (size_t)(n0 + sr) * K + sh * 16) : nullptr;
    bool bstage = (sr < BN);

    int lane = tid & 63, wid = tid >> 6;
    int wr = wid >> 1, wc = wid & 1;
    int lm = lane & 15, lk = (lane >> 4) * 8;

    f32x4 acc[4][NJ] = {};
    f32x4 acc2[DUAL ? 4 : 1][NJ] = {};

    for (int k0 = 0; k0 < K; k0 += 32) {
        float4 av[4] = {};
        float4 bv[4] = {};
        float4 bv2[4] = {};
        if (avalid) {
            const float4* ap = (const float4*)(asrc + k0);
            av[0] = ap[0]; av[1] = ap[1]; av[2] = ap[2]; av[3] = ap[3];
        }
        if (bstage) {
            const float4* bp = (const float4*)(b1src + k0);
            bv[0] = bp[0]; bv[1] = bp[1]; bv[2] = bp[2]; bv[3] = bp[3];
            if (DUAL) {
                const float4* bp2 = (const float4*)(b2src + k0);
                bv2[0] = bp2[0]; bv2[1] = bp2[1]; bv2[2] = bp2[2]; bv2[3] = bp2[3];
            }
        }
        __syncthreads();   // previous iteration's frag reads done before overwrite
        {
            const float* af_ = (const float*)av;
            short8 p0, p1;
#pragma unroll
            for (int u = 0; u < 8; ++u) p0[u] = toBF(af_[u]);
#pragma unroll
            for (int u = 0; u < 8; ++u) p1[u] = toBF(af_[8 + u]);
            *(short8*)&As[sr][sh * 16]     = p0;
            *(short8*)&As[sr][sh * 16 + 8] = p1;
        }
        if (bstage) {
            const float* bf_ = (const float*)bv;
            short8 p0, p1;
#pragma unroll
            for (int u = 0; u < 8; ++u) p0[u] = toBF(bf_[u]);
#pragma unroll
            for (int u = 0; u < 8; ++u) p1[u] = toBF(bf_[8 + u]);
            *(short8*)&Bs1[sr][sh * 16]     = p0;
            *(short8*)&Bs1[sr][sh * 16 + 8] = p1;
            if (DUAL) {
                const float* b2_ = (const float*)bv2;
                short8 q0, q1;
#pragma unroll
                for (int u = 0; u < 8; ++u) q0[u] = toBF(b2_[u]);
#pragma unroll
                for (int u = 0; u < 8; ++u) q1[u] = toBF(b2_[8 + u]);
                *(short8*)&Bs2[sr][sh * 16]     = q0;
                *(short8*)&Bs2[sr][sh * 16 + 8] = q1;
            }
        }
        __syncthreads();
        short8 af[4], bf1[NJ], bf2[NJ];
#pragma unroll
        for (int i = 0; i < 4; ++i) af[i] = *(const short8*)&As[wr * 64 + i * 16 + lm][lk];
#pragma unroll
        for (int j = 0; j < NJ; ++j) {
            bf1[j] = *(const short8*)&Bs1[wc * (BN / 2) + j * 16 + lm][lk];
            if (DUAL) bf2[j] = *(const short8*)&Bs2[wc * (BN / 2) + j * 16 + lm][lk];
        }
#pragma unroll
        for (int i = 0; i < 4; ++i)
#pragma unroll
            for (int j = 0; j < NJ; ++j) {
                acc[i][j] = __builtin_amdgcn_mfma_f32_16x16x32_bf16(af[i], bf1[j], acc[i][j], 0, 0, 0);
                if (DUAL)
                    acc2[i][j] = __builtin_amdgcn_mfma_f32_16x16x32_bf16(af[i], bf2[j], acc2[i][j], 0, 0, 0);
            }
    }

    // ---- epilogue ----
#pragma unroll
    for (int i = 0; i < 4; ++i) {
#pragma unroll
        for (int j = 0; j < NJ; ++j) {
            int mloc0 = wr * 64 + i * 16 + (lane >> 4) * 4;
            int n = n0 + wc * (BN / 2) + j * 16 + lm;
#pragma unroll
            for (int r = 0; r < 4; ++r) {
                int ml = mloc0 + r;
                float v = acc[i][j][r];
                if (EPI == 0) {
                    size_t m = (size_t)(mbase + ml);
                    C[m * N + n] = v;
                } else if (EPI == 1) {
                    size_t m = (size_t)(mbase + ml);
                    C[m * N + n] = v + res[m * N + n];
                } else if (EPI == 2) {
                    int mrow = mbase + ml;
                    if (mrow < ne) {
                        size_t s = (size_t)(oe + mrow);
                        C[s * N + n] = bucket_w[s] * v;
                    }
                } else if (EPI == 3) {
                    size_t m = (size_t)(mbase + ml);
                    int s0 = slot_of[2 * m], s1 = slot_of[2 * m + 1];
                    C[m * N + n] += v + yslot[(size_t)s0 * N + n] + yslot[(size_t)s1 * N + n];
                } else if (EPI == 4) {
                    size_t m = (size_t)(mbase + ml);
                    float g = v, u = acc2[i][j][r];
                    C[m * N + n] = (g / (1.f + __expf(-g))) * u;
                } else {
                    int mrow = mbase + ml;
                    if (mrow < ne) {
                        size_t s = (size_t)(oe + mrow);
                        float g = v, u = acc2[i][j][r];
                        C[s * N + n] = (g / (1.f + __expf(-g))) * u;
                    }
                }
            }
        }
    }
}

// ---------------- flash attention v2: 256 threads/block, 4 threads per q-row ----------------
__global__ __launch_bounds__(256) void attn_kernel(const float* __restrict__ q,
                                                   const float* __restrict__ k,
                                                   const float* __restrict__ v,
                                                   float* __restrict__ ctx) {
    int qt = blockIdx.x, h = blockIdx.y, b = blockIdx.z;
    int tid = threadIdx.x;
    int r = tid >> 2;        // q-row within tile (0..63)
    int ds = tid & 3;        // d-slice (0..3), 16 dims each
    int row = qt * 64 + r;
    const float* qr = q + ((size_t)(b * TS + row)) * TH + h * THD + ds * 16;
    float qreg[16];
#pragma unroll
    for (int u4 = 0; u4 < 4; ++u4) {
        float4 t4 = *(const float4*)(qr + u4 * 4);
        qreg[u4 * 4 + 0] = t4.x; qreg[u4 * 4 + 1] = t4.y;
        qreg[u4 * 4 + 2] = t4.z; qreg[u4 * 4 + 3] = t4.w;
    }
    float O[16];
#pragma unroll
    for (int d = 0; d < 16; ++d) O[d] = 0.f;
    float mrun = -1e30f, lrun = 0.f;
    __shared__ float Ks[16][68];
    __shared__ float Vs[16][68];
    int lr = tid >> 4;            // 0..15 load row
    int lc = (tid & 15) * 4;      // 0..60 load col
    for (int j0 = 0; j0 < TS; j0 += 16) {
        const float* kr = k + ((size_t)(b * TS + j0 + lr)) * TH + h * THD + lc;
        const float* vr = v + ((size_t)(b * TS + j0 + lr)) * TH + h * THD + lc;
        float4 kv4 = *(const float4*)kr;
        float4 vv4 = *(const float4*)vr;
        __syncthreads();   // protect LDS from previous iteration's readers
        *(float4*)&Ks[lr][lc] = kv4;
        *(float4*)&Vs[lr][lc] = vv4;
        __syncthreads();
        float s[16];
        float tmax = -1e30f;
#pragma unroll
        for (int j = 0; j < 16; ++j) {
            float acc = 0.f;
#pragma unroll
            for (int d = 0; d < 16; ++d) acc += qreg[d] * Ks[j][ds * 16 + d];
            acc += __shfl_xor(acc, 1);
            acc += __shfl_xor(acc, 2);
            acc *= 0.125f;
            s[j] = acc;
            tmax = fmaxf(tmax, acc);
        }
        float mnew = fmaxf(mrun, tmax);
        float corr = __expf(mrun - mnew);
        float p[16];
        float psum = 0.f;
#pragma unroll
        for (int j = 0; j < 16; ++j) { p[j] = __expf(s[j] - mnew); psum += p[j]; }
        lrun = lrun * corr + psum;
        mrun = mnew;
#pragma unroll
        for (int d = 0; d < 16; ++d) O[d] *= corr;
#pragma unroll
        for (int j = 0; j < 16; ++j) {
            float pj = p[j];
#pragma unroll
            for (int d = 0; d < 16; ++d) O[d] += pj * Vs[j][ds * 16 + d];
        }
    }
    float inv = 1.f / lrun;
    float* cr = ctx + ((size_t)(b * TS + row)) * TH + h * THD + ds * 16;
#pragma unroll
    for (int u4 = 0; u4 < 4; ++u4) {
        float4 o4;
        o4.x = O[u4 * 4 + 0] * inv; o4.y = O[u4 * 4 + 1] * inv;
        o4.z = O[u4 * 4 + 2] * inv; o4.w = O[u4 * 4 + 3] * inv;
        *(float4*)(cr + u4 * 4) = o4;
    }
}

// ---------------- gate + top2 ----------------
__global__ __launch_bounds__(64) void gate_topk_kernel(const float* __restrict__ xn2,
                                                       const float* __restrict__ gate_w,
                                                       float* __restrict__ tk_w,
                                                       int* __restrict__ tk_e,
                                                       int* __restrict__ counts) {
    int t = blockIdx.x;
    int lane = threadIdx.x;
    const float* xr = xn2 + (size_t)t * TH;
    float xv[12];
#pragma unroll
    for (int i = 0; i < 12; ++i) xv[i] = xr[lane + 64 * i];
    __shared__ float logits[TE];
    for (int e = 0; e < TE; ++e) {
        const float* gw = gate_w + (size_t)e * TH;
        float acc = 0.f;
#pragma unroll
        for (int i = 0; i < 12; ++i) acc += xv[i] * gw[lane + 64 * i];
#pragma unroll
        for (int off = 32; off > 0; off >>= 1) acc += __shfl_down(acc, off);
        if (lane == 0) logits[e] = acc;
    }
    __syncthreads();
    if (lane == 0) {
        float mx = -1e30f;
        for (int e = 0; e < TE; ++e) mx = fmaxf(mx, logits[e]);
        float ex[TE];
        float sum = 0.f;
        for (int e = 0; e < TE; ++e) { ex[e] = __expf(logits[e] - mx); sum += ex[e]; }
        int e0 = 0; float p0 = -1.f;
        for (int e = 0; e < TE; ++e) if (ex[e] > p0) { p0 = ex[e]; e0 = e; }
        int e1 = -1; float p1 = -1.f;
        for (int e = 0; e < TE; ++e) if (e != e0 && ex[e] > p1) { p1 = ex[e]; e1 = e; }
        float w0 = p0 / sum, w1 = p1 / sum;
        float denom = w0 + w1 + 1e-20f;
        tk_e[2 * t] = e0; tk_e[2 * t + 1] = e1;
        tk_w[2 * t] = w0 / denom; tk_w[2 * t + 1] = w1 / denom;
        atomicAdd(&counts[e0], 1);
        atomicAdd(&counts[e1], 1);
    }
}

__global__ void scan_kernel(const int* __restrict__ counts, int* __restrict__ offsets,
                            int* __restrict__ fill) {
    if (threadIdx.x == 0) {
        int run = 0;
        for (int e = 0; e < TE; ++e) { offsets[e] = run; fill[e] = run; run += counts[e]; }
    }
}

__global__ void scatter_kernel(const int* __restrict__ tk_e, const float* __restrict__ tk_w,
                               int* __restrict__ fill, int* __restrict__ bucket_tok,
                               float* __restrict__ bucket_w, int* __restrict__ slot_of) {
    int t = blockIdx.x * blockDim.x + threadIdx.x;
    if (t >= TT) return;
    for (int kk = 0; kk < TKK; ++kk) {
        int e = tk_e[2 * t + kk];
        int pos = atomicAdd(&fill[e], 1);
        bucket_tok[pos] = t;
        bucket_w[pos] = tk_w[2 * t + kk];
        slot_of[2 * t + kk] = pos;
    }
}

extern "C" void kernel_launch(void* const* d_in, const int* in_sizes, int n_in,
                              void* d_out, int out_size, void* d_ws, size_t ws_size,
                              hipStream_t stream) {
    const float* hidden  = (const float*)d_in[0];
    const float* norm1_w = (const float*)d_in[1];
    const float* Wq      = (const float*)d_in[2];
    const float* Wk      = (const float*)d_in[3];
    const float* Wv      = (const float*)d_in[4];
    const float* Wo      = (const float*)d_in[5];
    const float* norm2_w = (const float*)d_in[6];
    const float* gate_w  = (const float*)d_in[7];
    const float* Weg     = (const float*)d_in[8];
    const float* Weu     = (const float*)d_in[9];
    const float* Wed     = (const float*)d_in[10];
    const float* Wsg     = (const float*)d_in[11];
    const float* Wsu     = (const float*)d_in[12];
    const float* Wsd     = (const float*)d_in[13];
    float* out = (float*)d_out;

    const size_t BUF = (size_t)TT * TH;  // 3,145,728 floats
    float* ws  = (float*)d_ws;
    float* xn1  = ws;             // buf0
    float* qb   = ws + 1 * BUF;   // buf1; later act (TT*TKK*TF == BUF)
    float* kb   = ws + 2 * BUF;   // buf2; later yslot (spans buf2+buf3)
    float* vb   = ws + 3 * BUF;   // buf3
    float* ctxb = ws + 4 * BUF;   // buf4; later sact
    float* xn2  = ws + 5 * BUF;   // buf5
    char* tail = (char*)(ws + 6 * BUF);
    int*   tk_e       = (int*)tail;
    float* tk_w       = (float*)(tail + (size_t)TT * 2 * 4);
    int*   slot_of    = (int*)(tail + (size_t)TT * 2 * 8);
    int*   bucket_tok = (int*)(tail + (size_t)TT * 2 * 12);
    float* bucket_w   = (float*)(tail + (size_t)TT * 2 * 16);
    int*   counts     = (int*)(tail + (size_t)TT * 2 * 20);
    int*   offsets    = counts + 8;
    int*   fill       = counts + 16;

    float* act   = qb;
    float* yslot = kb;
    float* sact  = ctxb;

    hipMemsetAsync(counts, 0, 8 * sizeof(int), stream);

    rmsnorm_kernel<<<TT, 256, 0, stream>>>(hidden, norm1_w, xn1);

    // QKV: M=4096, N=768, K=768
    dim3 g1(TH / 128, TT / 128);
    mfma_gemm_kernel<0><<<g1, 256, 0, stream>>>(xn1, Wq, nullptr, qb, nullptr,
        nullptr, nullptr, nullptr, nullptr, nullptr, nullptr, TH, TH);
    mfma_gemm_kernel<0><<<g1, 256, 0, stream>>>(xn1, Wk, nullptr, kb, nullptr,
        nullptr, nullptr, nullptr, nullptr, nullptr, nullptr, TH, TH);
    mfma_gemm_kernel<0><<<g1, 256, 0, stream>>>(xn1, Wv, nullptr, vb, nullptr,
        nullptr, nullptr, nullptr, nullptr, nullptr, nullptr, TH, TH);

    dim3 ga(TS / 64, TNH, TB);
    attn_kernel<<<ga, 256, 0, stream>>>(qb, kb, vb, ctxb);

    // Wo + residual
    mfma_gemm_kernel<1><<<g1, 256, 0, stream>>>(ctxb, Wo, nullptr, out, hidden,
        nullptr, nullptr, nullptr, nullptr, nullptr, nullptr, TH, TH);

    rmsnorm_kernel<<<TT, 256, 0, stream>>>(out, norm2_w, xn2);

    gate_topk_kernel<<<TT, 64, 0, stream>>>(xn2, gate_w, tk_w, tk_e, counts);
    scan_kernel<<<1, 64, 0, stream>>>(counts, offsets, fill);
    scatter_kernel<<<(TT + 255) / 256, 256, 0, stream>>>(tk_e, tk_w, fill, bucket_tok, bucket_w, slot_of);

    // MoE up: dual-B + gather + SwiGLU. N=384, K=768, expert rows <= 8192 -> grid.y = 64
    mfma_gemm_kernel<5><<<dim3(TF / 64, TT * TKK / 128, TE), 256, 0, stream>>>(
        xn2, Weg, Weu, act, nullptr,
        bucket_tok, offsets, counts, nullptr, nullptr, nullptr, TF, TH);
    // MoE down: per-slot scale. N=768, K=384
    mfma_gemm_kernel<2><<<dim3(TH / 128, TT * TKK / 128, TE), 256, 0, stream>>>(
        act, Wed, nullptr, yslot, nullptr,
        nullptr, offsets, counts, bucket_w, nullptr, nullptr, TH, TF);

    // shared expert up: dual-B SwiGLU. N=768(SF), K=768
    mfma_gemm_kernel<4><<<dim3(TSF / 64, TT / 128), 256, 0, stream>>>(
        xn2, Wsg, Wsu, sact, nullptr,
        nullptr, nullptr, nullptr, nullptr, nullptr, nullptr, TSF, TH);
    // final: out += sact@Wsd^T + yslot[s0] + yslot[s1]. N=768, K=768
    mfma_gemm_kernel<3><<<dim3(TH / 128, TT / 128), 256, 0, stream>>>(
        sact, Wsd, nullptr, out, nullptr,
        nullptr, nullptr, nullptr, nullptr, yslot, slot_of, TH, TSF);
}

// Round 9
// 643.405 us; speedup vs baseline: 3.4204x; 1.4193x over previous
//
#include <hip/hip_runtime.h>
#include <hip/hip_bf16.h>

#define TB 4
#define TS 1024
#define TH 768
#define TNH 12
#define THD 64
#define TE 8
#define TKK 2
#define TF 384
#define TSF 768
#define TT (TB*TS)
#define REPS 1e-6f

typedef __attribute__((ext_vector_type(8))) short short8;   // 8 bf16 = 4 VGPRs (MFMA A/B frag)
typedef __attribute__((ext_vector_type(4))) float f32x4;    // MFMA C/D frag

__device__ inline short toBF(float f) {
    __hip_bfloat16 h = __float2bfloat16(f);
    return *reinterpret_cast<short*>(&h);
}

// ---------------- RMSNorm: one block per token ----------------
__global__ __launch_bounds__(256) void rmsnorm_kernel(const float* __restrict__ x,
                                                      const float* __restrict__ w,
                                                      float* __restrict__ out) {
    int t = blockIdx.x;
    int tid = threadIdx.x;
    const float* xr = x + (size_t)t * TH;
    float v0 = xr[tid], v1 = xr[tid + 256], v2 = xr[tid + 512];
    float ss = v0 * v0 + v1 * v1 + v2 * v2;
    __shared__ float red[256];
    red[tid] = ss;
    __syncthreads();
    for (int s = 128; s > 0; s >>= 1) {
        if (tid < s) red[tid] += red[tid + s];
        __syncthreads();
    }
    float scale = rsqrtf(red[0] / (float)TH + REPS);
    float* o = out + (size_t)t * TH;
    o[tid]       = w[tid] * v0 * scale;
    o[tid + 256] = w[tid + 256] * v1 * scale;
    o[tid + 512] = w[tid + 512] * v2 * scale;
}

// ---------------- MFMA GEMM-BT (unchanged from verified Round-6 kernel) ----------
template <int EPI>
__global__ __launch_bounds__(256) void mfma_gemm_kernel(
    const float* __restrict__ A, const float* __restrict__ B1, const float* __restrict__ B2,
    float* __restrict__ C, const float* __restrict__ res,
    const int* __restrict__ rowmap, const int* __restrict__ offsets,
    const int* __restrict__ counts, const float* __restrict__ bucket_w,
    const float* __restrict__ yslot, const int* __restrict__ slot_of,
    int N, int K)
{
    constexpr bool DUAL = (EPI >= 4);
    constexpr bool EXPERT = (EPI == 2 || EPI == 5);
    constexpr int BN = DUAL ? 64 : 128;
    constexpr int NJ = DUAL ? 2 : 4;

    __shared__ short As[128][40];
    __shared__ short Bs1[BN][40];
    __shared__ short Bs2[DUAL ? BN : 1][40];

    int tid = threadIdx.x;
    int e = blockIdx.z;
    int ne = 0x7fffffff, oe = 0;
    if (EXPERT) { ne = counts[e]; oe = offsets[e]; }
    int mbase = blockIdx.y * 128;
    if (EXPERT && mbase >= ne) return;
    int n0 = blockIdx.x * BN;

    int sr = tid >> 1;
    int sh = tid & 1;
    size_t arow = 0; bool avalid = true;
    if (EPI == 5) {
        int mrow = mbase + sr;
        int tok = (mrow < ne) ? rowmap[oe + mrow] : -1;
        avalid = tok >= 0; arow = (tok >= 0) ? (size_t)tok : 0;
    } else if (EPI == 2) {
        int mrow = mbase + sr;
        avalid = mrow < ne; arow = (size_t)(oe + mrow);
    } else {
        arow = (size_t)(mbase + sr);
    }
    const float* asrc = A + arow * K + sh * 16;
    size_t bOff = (size_t)e * (size_t)N * K;
    const float* b1src = B1 + bOff + (size_t)(n0 + sr) * K + sh * 16;
    const float* b2src = DUAL ? (B2 + bOff + (size_t)(n0 + sr) * K + sh * 16) : nullptr;
    bool bstage = (sr < BN);

    int lane = tid & 63, wid = tid >> 6;
    int wr = wid >> 1, wc = wid & 1;
    int lm = lane & 15, lk = (lane >> 4) * 8;

    f32x4 acc[4][NJ] = {};
    f32x4 acc2[DUAL ? 4 : 1][NJ] = {};

    for (int k0 = 0; k0 < K; k0 += 32) {
        float4 av[4] = {};
        float4 bv[4] = {};
        float4 bv2[4] = {};
        if (avalid) {
            const float4* ap = (const float4*)(asrc + k0);
            av[0] = ap[0]; av[1] = ap[1]; av[2] = ap[2]; av[3] = ap[3];
        }
        if (bstage) {
            const float4* bp = (const float4*)(b1src + k0);
            bv[0] = bp[0]; bv[1] = bp[1]; bv[2] = bp[2]; bv[3] = bp[3];
            if (DUAL) {
                const float4* bp2 = (const float4*)(b2src + k0);
                bv2[0] = bp2[0]; bv2[1] = bp2[1]; bv2[2] = bp2[2]; bv2[3] = bp2[3];
            }
        }
        __syncthreads();
        {
            const float* af_ = (const float*)av;
            short8 p0, p1;
#pragma unroll
            for (int u = 0; u < 8; ++u) p0[u] = toBF(af_[u]);
#pragma unroll
            for (int u = 0; u < 8; ++u) p1[u] = toBF(af_[8 + u]);
            *(short8*)&As[sr][sh * 16]     = p0;
            *(short8*)&As[sr][sh * 16 + 8] = p1;
        }
        if (bstage) {
            const float* bf_ = (const float*)bv;
            short8 p0, p1;
#pragma unroll
            for (int u = 0; u < 8; ++u) p0[u] = toBF(bf_[u]);
#pragma unroll
            for (int u = 0; u < 8; ++u) p1[u] = toBF(bf_[8 + u]);
            *(short8*)&Bs1[sr][sh * 16]     = p0;
            *(short8*)&Bs1[sr][sh * 16 + 8] = p1;
            if (DUAL) {
                const float* b2_ = (const float*)bv2;
                short8 q0, q1;
#pragma unroll
                for (int u = 0; u < 8; ++u) q0[u] = toBF(b2_[u]);
#pragma unroll
                for (int u = 0; u < 8; ++u) q1[u] = toBF(b2_[8 + u]);
                *(short8*)&Bs2[sr][sh * 16]     = q0;
                *(short8*)&Bs2[sr][sh * 16 + 8] = q1;
            }
        }
        __syncthreads();
        short8 af[4], bf1[NJ], bf2[NJ];
#pragma unroll
        for (int i = 0; i < 4; ++i) af[i] = *(const short8*)&As[wr * 64 + i * 16 + lm][lk];
#pragma unroll
        for (int j = 0; j < NJ; ++j) {
            bf1[j] = *(const short8*)&Bs1[wc * (BN / 2) + j * 16 + lm][lk];
            if (DUAL) bf2[j] = *(const short8*)&Bs2[wc * (BN / 2) + j * 16 + lm][lk];
        }
#pragma unroll
        for (int i = 0; i < 4; ++i)
#pragma unroll
            for (int j = 0; j < NJ; ++j) {
                acc[i][j] = __builtin_amdgcn_mfma_f32_16x16x32_bf16(af[i], bf1[j], acc[i][j], 0, 0, 0);
                if (DUAL)
                    acc2[i][j] = __builtin_amdgcn_mfma_f32_16x16x32_bf16(af[i], bf2[j], acc2[i][j], 0, 0, 0);
            }
    }

#pragma unroll
    for (int i = 0; i < 4; ++i) {
#pragma unroll
        for (int j = 0; j < NJ; ++j) {
            int mloc0 = wr * 64 + i * 16 + (lane >> 4) * 4;
            int n = n0 + wc * (BN / 2) + j * 16 + lm;
#pragma unroll
            for (int r = 0; r < 4; ++r) {
                int ml = mloc0 + r;
                float v = acc[i][j][r];
                if (EPI == 0) {
                    size_t m = (size_t)(mbase + ml);
                    C[m * N + n] = v;
                } else if (EPI == 1) {
                    size_t m = (size_t)(mbase + ml);
                    C[m * N + n] = v + res[m * N + n];
                } else if (EPI == 2) {
                    int mrow = mbase + ml;
                    if (mrow < ne) {
                        size_t s = (size_t)(oe + mrow);
                        C[s * N + n] = bucket_w[s] * v;
                    }
                } else if (EPI == 3) {
                    size_t m = (size_t)(mbase + ml);
                    int s0 = slot_of[2 * m], s1 = slot_of[2 * m + 1];
                    C[m * N + n] += v + yslot[(size_t)s0 * N + n] + yslot[(size_t)s1 * N + n];
                } else if (EPI == 4) {
                    size_t m = (size_t)(mbase + ml);
                    float g = v, u = acc2[i][j][r];
                    C[m * N + n] = (g / (1.f + __expf(-g))) * u;
                } else {
                    int mrow = mbase + ml;
                    if (mrow < ne) {
                        size_t s = (size_t)(oe + mrow);
                        float g = v, u = acc2[i][j][r];
                        C[s * N + n] = (g / (1.f + __expf(-g))) * u;
                    }
                }
            }
        }
    }
}

// ---------------- MFMA flash attention ----------------
// Block = 64 q-rows of one (b,h). 4 waves; wave owns 16 q-rows. KV tile = 64.
// Q in registers (A-frags). K in LDS row-major bf16, XOR-swizzled (byte ^= (row&7)<<4).
// V in LDS TRANSPOSED Vt[d][kv] bf16, same swizzle (PV B-frag needs V columns).
// P: D-layout -> wave-private LDS tile -> A-frag reads (same swizzle).
// Online softmax per q-row in fp32; row data lives in the 16-lane group (lane>>4
// fixed), reduced with __shfl_xor masks 1,2,4,8. MFMA layouts per m89 (verified
// by the GEMM above): A/B lane = row/col lane&15, k-base (lane>>4)*8; D col=lane&15,
// row=(lane>>4)*4+reg.
__global__ __launch_bounds__(256) void attn_mfma_kernel(const float* __restrict__ q,
                                                        const float* __restrict__ k,
                                                        const float* __restrict__ v,
                                                        float* __restrict__ ctx) {
    int qt = blockIdx.x, h = blockIdx.y, b = blockIdx.z;
    int tid = threadIdx.x;
    int lane = tid & 63, wid = tid >> 6;
    int lm = lane & 15, hi = lane >> 4;

    __shared__ short Ks[64 * 64];      // 8 KB, row stride 128 B (swizzled)
    __shared__ short Vt[64 * 64];      // 8 KB, row = d, col = kv (swizzled)
    __shared__ short Ps[4][16 * 64];   // 8 KB, per-wave P tile (swizzled)

    // ---- Q fragments (held for the whole kernel) ----
    int qrow = qt * 64 + wid * 16 + lm;
    const float* qptr = q + ((size_t)(b * TS + qrow)) * TH + h * THD;
    short8 qf[2];
#pragma unroll
    for (int ksl = 0; ksl < 2; ++ksl) {
        const float4* qp = (const float4*)(qptr + ksl * 32 + hi * 8);
        float4 a = qp[0], c = qp[1];
        short8 p;
        p[0] = toBF(a.x); p[1] = toBF(a.y); p[2] = toBF(a.z); p[3] = toBF(a.w);
        p[4] = toBF(c.x); p[5] = toBF(c.y); p[6] = toBF(c.z); p[7] = toBF(c.w);
        qf[ksl] = p;
    }

    f32x4 oacc[4] = {};                 // [nsub] -> O[16 q][64 d]
    float mrun[4] = {-1e30f, -1e30f, -1e30f, -1e30f};
    float lrun[4] = {0.f, 0.f, 0.f, 0.f};

    // staging coords
    int kr = tid >> 2, kc = (tid & 3) * 16;           // K: row, col-base (16 dims)
    const float* ksrc = k + ((size_t)(b * TS + kr)) * TH + h * THD + kc;
    int kv0 = (tid & 31) * 2, vd0 = (tid >> 5) * 8;   // V: kv pair, 8-dim block
    const float* vsrc = v + ((size_t)(b * TS + kv0)) * TH + h * THD + vd0;

    for (int j0 = 0; j0 < TS; j0 += 64) {
        // ---- global loads (K tile row-major, V tile for transpose) ----
        const float4* kp = (const float4*)(ksrc + (size_t)j0 * TH);
        float4 kv4[4] = {kp[0], kp[1], kp[2], kp[3]};
        const float4* vp0 = (const float4*)(vsrc + (size_t)j0 * TH);
        const float4* vp1 = (const float4*)(vsrc + (size_t)(j0 + 1) * TH);
        float4 va0 = vp0[0], va1 = vp0[1];   // V[kv0][vd0..+7]
        float4 vb0 = vp1[0], vb1 = vp1[1];   // V[kv0+1][vd0..+7]
        __syncthreads();   // previous tile's LDS reads complete
        // ---- write Ks (2x short8, swizzled) ----
#pragma unroll
        for (int w = 0; w < 2; ++w) {
            const float* src = (const float*)&kv4[2 * w];
            short8 p;
#pragma unroll
            for (int u = 0; u < 8; ++u) p[u] = toBF(src[u]);
            int off = (kr * 128 + (kc + 8 * w) * 2) ^ ((kr & 7) << 4);
            *(short8*)((char*)Ks + off) = p;
        }
        // ---- write Vt transposed (8x b32, 2 kv packed, swizzled) ----
        {
            const float* a_ = (const float*)&va0;  // kv0   dims vd0..vd0+7
            const float* b_ = (const float*)&vb0;  // kv0+1
#pragma unroll
            for (int i = 0; i < 8; ++i) {
                float fa = (i < 4) ? a_[i] : ((const float*)&va1)[i - 4];
                float fb = (i < 4) ? b_[i] : ((const float*)&vb1)[i - 4];
                int d = vd0 + i;
                unsigned pk = (unsigned)(unsigned short)toBF(fa)
                            | ((unsigned)(unsigned short)toBF(fb) << 16);
                int off = (d * 128 + kv0 * 2) ^ ((d & 7) << 4);
                *(unsigned*)((char*)Vt + off) = pk;
            }
        }
        __syncthreads();
        // ---- QK^T: S[16 q][64 kv] ----
        f32x4 sacc[4] = {};
#pragma unroll
        for (int ksl = 0; ksl < 2; ++ksl) {
#pragma unroll
            for (int jsub = 0; jsub < 4; ++jsub) {
                int rowb = jsub * 16 + lm;
                int off = (rowb * 128 + ksl * 64 + hi * 16) ^ ((rowb & 7) << 4);
                short8 bk = *(const short8*)((const char*)Ks + off);
                sacc[jsub] = __builtin_amdgcn_mfma_f32_16x16x32_bf16(qf[ksl], bk, sacc[jsub], 0, 0, 0);
            }
        }
        // ---- online softmax (scaled domain) ----
#pragma unroll
        for (int jsub = 0; jsub < 4; ++jsub)
#pragma unroll
            for (int r = 0; r < 4; ++r) sacc[jsub][r] *= 0.125f;
#pragma unroll
        for (int r = 0; r < 4; ++r) {
            float tm = fmaxf(fmaxf(sacc[0][r], sacc[1][r]), fmaxf(sacc[2][r], sacc[3][r]));
            tm = fmaxf(tm, __shfl_xor(tm, 1));
            tm = fmaxf(tm, __shfl_xor(tm, 2));
            tm = fmaxf(tm, __shfl_xor(tm, 4));
            tm = fmaxf(tm, __shfl_xor(tm, 8));
            float mnew = fmaxf(mrun[r], tm);
            float corr = __expf(mrun[r] - mnew);
            mrun[r] = mnew;
            float rs = 0.f;
#pragma unroll
            for (int jsub = 0; jsub < 4; ++jsub) {
                float p = __expf(sacc[jsub][r] - mnew);
                sacc[jsub][r] = p;
                rs += p;
            }
            rs += __shfl_xor(rs, 1);
            rs += __shfl_xor(rs, 2);
            rs += __shfl_xor(rs, 4);
            rs += __shfl_xor(rs, 8);
            lrun[r] = lrun[r] * corr + rs;
#pragma unroll
            for (int nsub = 0; nsub < 4; ++nsub) oacc[nsub][r] *= corr;
        }
        // ---- P -> wave-private LDS (D-layout scatter, swizzled) ----
        char* psw = (char*)Ps[wid];
#pragma unroll
        for (int jsub = 0; jsub < 4; ++jsub)
#pragma unroll
            for (int r = 0; r < 4; ++r) {
                int row = hi * 4 + r;
                int col = jsub * 16 + lm;
                int off = (row * 128 + col * 2) ^ ((row & 7) << 4);
                *(short*)(psw + off) = toBF(sacc[jsub][r]);
            }
        // ---- read P as A-frags, PV MFMAs ----
#pragma unroll
        for (int ksl = 0; ksl < 2; ++ksl) {
            int offp = (lm * 128 + ksl * 64 + hi * 16) ^ ((lm & 7) << 4);
            short8 pa = *(const short8*)((const char*)psw + offp);
#pragma unroll
            for (int nsub = 0; nsub < 4; ++nsub) {
                int rowb = nsub * 16 + lm;
                int offv = (rowb * 128 + ksl * 64 + hi * 16) ^ ((rowb & 7) << 4);
                short8 bv = *(const short8*)((const char*)Vt + offv);
                oacc[nsub] = __builtin_amdgcn_mfma_f32_16x16x32_bf16(pa, bv, oacc[nsub], 0, 0, 0);
            }
        }
    }
    // ---- epilogue: O /= l ----
    float inv[4];
#pragma unroll
    for (int r = 0; r < 4; ++r) inv[r] = 1.f / lrun[r];
#pragma unroll
    for (int r = 0; r < 4; ++r) {
        int row = qt * 64 + wid * 16 + hi * 4 + r;
        float* cp = ctx + ((size_t)(b * TS + row)) * TH + h * THD;
#pragma unroll
        for (int nsub = 0; nsub < 4; ++nsub)
            cp[nsub * 16 + lm] = oacc[nsub][r] * inv[r];
    }
}

// ---------------- gate + top2 ----------------
__global__ __launch_bounds__(64) void gate_topk_kernel(const float* __restrict__ xn2,
                                                       const float* __restrict__ gate_w,
                                                       float* __restrict__ tk_w,
                                                       int* __restrict__ tk_e,
                                                       int* __restrict__ counts) {
    int t = blockIdx.x;
    int lane = threadIdx.x;
    const float* xr = xn2 + (size_t)t * TH;
    float xv[12];
#pragma unroll
    for (int i = 0; i < 12; ++i) xv[i] = xr[lane + 64 * i];
    __shared__ float logits[TE];
    for (int e = 0; e < TE; ++e) {
        const float* gw = gate_w + (size_t)e * TH;
        float acc = 0.f;
#pragma unroll
        for (int i = 0; i < 12; ++i) acc += xv[i] * gw[lane + 64 * i];
#pragma unroll
        for (int off = 32; off > 0; off >>= 1) acc += __shfl_down(acc, off);
        if (lane == 0) logits[e] = acc;
    }
    __syncthreads();
    if (lane == 0) {
        float mx = -1e30f;
        for (int e = 0; e < TE; ++e) mx = fmaxf(mx, logits[e]);
        float ex[TE];
        float sum = 0.f;
        for (int e = 0; e < TE; ++e) { ex[e] = __expf(logits[e] - mx); sum += ex[e]; }
        int e0 = 0; float p0 = -1.f;
        for (int e = 0; e < TE; ++e) if (ex[e] > p0) { p0 = ex[e]; e0 = e; }
        int e1 = -1; float p1 = -1.f;
        for (int e = 0; e < TE; ++e) if (e != e0 && ex[e] > p1) { p1 = ex[e]; e1 = e; }
        float w0 = p0 / sum, w1 = p1 / sum;
        float denom = w0 + w1 + 1e-20f;
        tk_e[2 * t] = e0; tk_e[2 * t + 1] = e1;
        tk_w[2 * t] = w0 / denom; tk_w[2 * t + 1] = w1 / denom;
        atomicAdd(&counts[e0], 1);
        atomicAdd(&counts[e1], 1);
    }
}

__global__ void scan_kernel(const int* __restrict__ counts, int* __restrict__ offsets,
                            int* __restrict__ fill) {
    if (threadIdx.x == 0) {
        int run = 0;
        for (int e = 0; e < TE; ++e) { offsets[e] = run; fill[e] = run; run += counts[e]; }
    }
}

__global__ void scatter_kernel(const int* __restrict__ tk_e, const float* __restrict__ tk_w,
                               int* __restrict__ fill, int* __restrict__ bucket_tok,
                               float* __restrict__ bucket_w, int* __restrict__ slot_of) {
    int t = blockIdx.x * blockDim.x + threadIdx.x;
    if (t >= TT) return;
    for (int kk = 0; kk < TKK; ++kk) {
        int e = tk_e[2 * t + kk];
        int pos = atomicAdd(&fill[e], 1);
        bucket_tok[pos] = t;
        bucket_w[pos] = tk_w[2 * t + kk];
        slot_of[2 * t + kk] = pos;
    }
}

extern "C" void kernel_launch(void* const* d_in, const int* in_sizes, int n_in,
                              void* d_out, int out_size, void* d_ws, size_t ws_size,
                              hipStream_t stream) {
    const float* hidden  = (const float*)d_in[0];
    const float* norm1_w = (const float*)d_in[1];
    const float* Wq      = (const float*)d_in[2];
    const float* Wk      = (const float*)d_in[3];
    const float* Wv      = (const float*)d_in[4];
    const float* Wo      = (const float*)d_in[5];
    const float* norm2_w = (const float*)d_in[6];
    const float* gate_w  = (const float*)d_in[7];
    const float* Weg     = (const float*)d_in[8];
    const float* Weu     = (const float*)d_in[9];
    const float* Wed     = (const float*)d_in[10];
    const float* Wsg     = (const float*)d_in[11];
    const float* Wsu     = (const float*)d_in[12];
    const float* Wsd     = (const float*)d_in[13];
    float* out = (float*)d_out;

    const size_t BUF = (size_t)TT * TH;  // 3,145,728 floats
    float* ws  = (float*)d_ws;
    float* xn1  = ws;             // buf0
    float* qb   = ws + 1 * BUF;   // buf1; later act (TT*TKK*TF == BUF)
    float* kb   = ws + 2 * BUF;   // buf2; later yslot (spans buf2+buf3)
    float* vb   = ws + 3 * BUF;   // buf3
    float* ctxb = ws + 4 * BUF;   // buf4; later sact
    float* xn2  = ws + 5 * BUF;   // buf5
    char* tail = (char*)(ws + 6 * BUF);
    int*   tk_e       = (int*)tail;
    float* tk_w       = (float*)(tail + (size_t)TT * 2 * 4);
    int*   slot_of    = (int*)(tail + (size_t)TT * 2 * 8);
    int*   bucket_tok = (int*)(tail + (size_t)TT * 2 * 12);
    float* bucket_w   = (float*)(tail + (size_t)TT * 2 * 16);
    int*   counts     = (int*)(tail + (size_t)TT * 2 * 20);
    int*   offsets    = counts + 8;
    int*   fill       = counts + 16;

    float* act   = qb;
    float* yslot = kb;
    float* sact  = ctxb;

    hipMemsetAsync(counts, 0, 8 * sizeof(int), stream);

    rmsnorm_kernel<<<TT, 256, 0, stream>>>(hidden, norm1_w, xn1);

    // QKV: M=4096, N=768, K=768
    dim3 g1(TH / 128, TT / 128);
    mfma_gemm_kernel<0><<<g1, 256, 0, stream>>>(xn1, Wq, nullptr, qb, nullptr,
        nullptr, nullptr, nullptr, nullptr, nullptr, nullptr, TH, TH);
    mfma_gemm_kernel<0><<<g1, 256, 0, stream>>>(xn1, Wk, nullptr, kb, nullptr,
        nullptr, nullptr, nullptr, nullptr, nullptr, nullptr, TH, TH);
    mfma_gemm_kernel<0><<<g1, 256, 0, stream>>>(xn1, Wv, nullptr, vb, nullptr,
        nullptr, nullptr, nullptr, nullptr, nullptr, nullptr, TH, TH);

    dim3 ga(TS / 64, TNH, TB);
    attn_mfma_kernel<<<ga, 256, 0, stream>>>(qb, kb, vb, ctxb);

    // Wo + residual
    mfma_gemm_kernel<1><<<g1, 256, 0, stream>>>(ctxb, Wo, nullptr, out, hidden,
        nullptr, nullptr, nullptr, nullptr, nullptr, nullptr, TH, TH);

    rmsnorm_kernel<<<TT, 256, 0, stream>>>(out, norm2_w, xn2);

    gate_topk_kernel<<<TT, 64, 0, stream>>>(xn2, gate_w, tk_w, tk_e, counts);
    scan_kernel<<<1, 64, 0, stream>>>(counts, offsets, fill);
    scatter_kernel<<<(TT + 255) / 256, 256, 0, stream>>>(tk_e, tk_w, fill, bucket_tok, bucket_w, slot_of);

    // MoE up: dual-B + gather + SwiGLU. N=384, K=768
    mfma_gemm_kernel<5><<<dim3(TF / 64, TT * TKK / 128, TE), 256, 0, stream>>>(
        xn2, Weg, Weu, act, nullptr,
        bucket_tok, offsets, counts, nullptr, nullptr, nullptr, TF, TH);
    // MoE down: per-slot scale. N=768, K=384
    mfma_gemm_kernel<2><<<dim3(TH / 128, TT * TKK / 128, TE), 256, 0, stream>>>(
        act, Wed, nullptr, yslot, nullptr,
        nullptr, offsets, counts, bucket_w, nullptr, nullptr, TH, TF);

    // shared expert up: dual-B SwiGLU. N=768(SF), K=768
    mfma_gemm_kernel<4><<<dim3(TSF / 64, TT / 128), 256, 0, stream>>>(
        xn2, Wsg, Wsu, sact, nullptr,
        nullptr, nullptr, nullptr, nullptr, nullptr, nullptr, TSF, TH);
    // final: out += sact@Wsd^T + yslot[s0] + yslot[s1]. N=768, K=768
    mfma_gemm_kernel<3><<<dim3(TH / 128, TT / 128), 256, 0, stream>>>(
        sact, Wsd, nullptr, out, nullptr,
        nullptr, nullptr, nullptr, nullptr, yslot, slot_of, TH, TSF);
}

// Round 11
// 521.685 us; speedup vs baseline: 4.2184x; 1.2333x over previous
//
#include <hip/hip_runtime.h>
#include <hip/hip_bf16.h>

#define TB 4
#define TS 1024
#define TH 768
#define TNH 12
#define THD 64
#define TE 8
#define TKK 2
#define TF 384
#define TSF 768
#define TT (TB*TS)
#define REPS 1e-6f

typedef __attribute__((ext_vector_type(8))) short short8;   // 8 bf16 = 4 VGPRs (MFMA A/B frag)
typedef __attribute__((ext_vector_type(4))) float f32x4;    // MFMA C/D frag

__device__ inline short toBF(float f) {
    __hip_bfloat16 h = __float2bfloat16(f);
    return *reinterpret_cast<short*>(&h);
}

// ---------------- RMSNorm: one block per token ----------------
__global__ __launch_bounds__(256) void rmsnorm_kernel(const float* __restrict__ x,
                                                      const float* __restrict__ w,
                                                      float* __restrict__ out) {
    int t = blockIdx.x;
    int tid = threadIdx.x;
    const float* xr = x + (size_t)t * TH;
    float v0 = xr[tid], v1 = xr[tid + 256], v2 = xr[tid + 512];
    float ss = v0 * v0 + v1 * v1 + v2 * v2;
    __shared__ float red[256];
    red[tid] = ss;
    __syncthreads();
    for (int s = 128; s > 0; s >>= 1) {
        if (tid < s) red[tid] += red[tid + s];
        __syncthreads();
    }
    float scale = rsqrtf(red[0] / (float)TH + REPS);
    float* o = out + (size_t)t * TH;
    o[tid]       = w[tid] * v0 * scale;
    o[tid + 256] = w[tid + 256] * v1 * scale;
    o[tid + 512] = w[tid + 512] * v2 * scale;
}

// ---------------- MFMA GEMM-BT (unchanged from verified Round-6 kernel) ----------
template <int EPI>
__global__ __launch_bounds__(256) void mfma_gemm_kernel(
    const float* __restrict__ A, const float* __restrict__ B1, const float* __restrict__ B2,
    float* __restrict__ C, const float* __restrict__ res,
    const int* __restrict__ rowmap, const int* __restrict__ offsets,
    const int* __restrict__ counts, const float* __restrict__ bucket_w,
    const float* __restrict__ yslot, const int* __restrict__ slot_of,
    int N, int K)
{
    constexpr bool DUAL = (EPI >= 4);
    constexpr bool EXPERT = (EPI == 2 || EPI == 5);
    constexpr int BN = DUAL ? 64 : 128;
    constexpr int NJ = DUAL ? 2 : 4;

    __shared__ short As[128][40];
    __shared__ short Bs1[BN][40];
    __shared__ short Bs2[DUAL ? BN : 1][40];

    int tid = threadIdx.x;
    int e = blockIdx.z;
    int ne = 0x7fffffff, oe = 0;
    if (EXPERT) { ne = counts[e]; oe = offsets[e]; }
    int mbase = blockIdx.y * 128;
    if (EXPERT && mbase >= ne) return;
    int n0 = blockIdx.x * BN;

    int sr = tid >> 1;
    int sh = tid & 1;
    size_t arow = 0; bool avalid = true;
    if (EPI == 5) {
        int mrow = mbase + sr;
        int tok = (mrow < ne) ? rowmap[oe + mrow] : -1;
        avalid = tok >= 0; arow = (tok >= 0) ? (size_t)tok : 0;
    } else if (EPI == 2) {
        int mrow = mbase + sr;
        avalid = mrow < ne; arow = (size_t)(oe + mrow);
    } else {
        arow = (size_t)(mbase + sr);
    }
    const float* asrc = A + arow * K + sh * 16;
    size_t bOff = (size_t)e * (size_t)N * K;
    const float* b1src = B1 + bOff + (size_t)(n0 + sr) * K + sh * 16;
    const float* b2src = DUAL ? (B2 + bOff + (size_t)(n0 + sr) * K + sh * 16) : nullptr;
    bool bstage = (sr < BN);

    int lane = tid & 63, wid = tid >> 6;
    int wr = wid >> 1, wc = wid & 1;
    int lm = lane & 15, lk = (lane >> 4) * 8;

    f32x4 acc[4][NJ] = {};
    f32x4 acc2[DUAL ? 4 : 1][NJ] = {};

    for (int k0 = 0; k0 < K; k0 += 32) {
        float4 av[4] = {};
        float4 bv[4] = {};
        float4 bv2[4] = {};
        if (avalid) {
            const float4* ap = (const float4*)(asrc + k0);
            av[0] = ap[0]; av[1] = ap[1]; av[2] = ap[2]; av[3] = ap[3];
        }
        if (bstage) {
            const float4* bp = (const float4*)(b1src + k0);
            bv[0] = bp[0]; bv[1] = bp[1]; bv[2] = bp[2]; bv[3] = bp[3];
            if (DUAL) {
                const float4* bp2 = (const float4*)(b2src + k0);
                bv2[0] = bp2[0]; bv2[1] = bp2[1]; bv2[2] = bp2[2]; bv2[3] = bp2[3];
            }
        }
        __syncthreads();
        {
            const float* af_ = (const float*)av;
            short8 p0, p1;
#pragma unroll
            for (int u = 0; u < 8; ++u) p0[u] = toBF(af_[u]);
#pragma unroll
            for (int u = 0; u < 8; ++u) p1[u] = toBF(af_[8 + u]);
            *(short8*)&As[sr][sh * 16]     = p0;
            *(short8*)&As[sr][sh * 16 + 8] = p1;
        }
        if (bstage) {
            const float* bf_ = (const float*)bv;
            short8 p0, p1;
#pragma unroll
            for (int u = 0; u < 8; ++u) p0[u] = toBF(bf_[u]);
#pragma unroll
            for (int u = 0; u < 8; ++u) p1[u] = toBF(bf_[8 + u]);
            *(short8*)&Bs1[sr][sh * 16]     = p0;
            *(short8*)&Bs1[sr][sh * 16 + 8] = p1;
            if (DUAL) {
                const float* b2_ = (const float*)bv2;
                short8 q0, q1;
#pragma unroll
                for (int u = 0; u < 8; ++u) q0[u] = toBF(b2_[u]);
#pragma unroll
                for (int u = 0; u < 8; ++u) q1[u] = toBF(b2_[8 + u]);
                *(short8*)&Bs2[sr][sh * 16]     = q0;
                *(short8*)&Bs2[sr][sh * 16 + 8] = q1;
            }
        }
        __syncthreads();
        short8 af[4], bf1[NJ], bf2[NJ];
#pragma unroll
        for (int i = 0; i < 4; ++i) af[i] = *(const short8*)&As[wr * 64 + i * 16 + lm][lk];
#pragma unroll
        for (int j = 0; j < NJ; ++j) {
            bf1[j] = *(const short8*)&Bs1[wc * (BN / 2) + j * 16 + lm][lk];
            if (DUAL) bf2[j] = *(const short8*)&Bs2[wc * (BN / 2) + j * 16 + lm][lk];
        }
#pragma unroll
        for (int i = 0; i < 4; ++i)
#pragma unroll
            for (int j = 0; j < NJ; ++j) {
                acc[i][j] = __builtin_amdgcn_mfma_f32_16x16x32_bf16(af[i], bf1[j], acc[i][j], 0, 0, 0);
                if (DUAL)
                    acc2[i][j] = __builtin_amdgcn_mfma_f32_16x16x32_bf16(af[i], bf2[j], acc2[i][j], 0, 0, 0);
            }
    }

#pragma unroll
    for (int i = 0; i < 4; ++i) {
#pragma unroll
        for (int j = 0; j < NJ; ++j) {
            int mloc0 = wr * 64 + i * 16 + (lane >> 4) * 4;
            int n = n0 + wc * (BN / 2) + j * 16 + lm;
#pragma unroll
            for (int r = 0; r < 4; ++r) {
                int ml = mloc0 + r;
                float v = acc[i][j][r];
                if (EPI == 0) {
                    size_t m = (size_t)(mbase + ml);
                    C[m * N + n] = v;
                } else if (EPI == 1) {
                    size_t m = (size_t)(mbase + ml);
                    C[m * N + n] = v + res[m * N + n];
                } else if (EPI == 2) {
                    int mrow = mbase + ml;
                    if (mrow < ne) {
                        size_t s = (size_t)(oe + mrow);
                        C[s * N + n] = bucket_w[s] * v;
                    }
                } else if (EPI == 3) {
                    size_t m = (size_t)(mbase + ml);
                    int s0 = slot_of[2 * m], s1 = slot_of[2 * m + 1];
                    C[m * N + n] += v + yslot[(size_t)s0 * N + n] + yslot[(size_t)s1 * N + n];
                } else if (EPI == 4) {
                    size_t m = (size_t)(mbase + ml);
                    float g = v, u = acc2[i][j][r];
                    C[m * N + n] = (g / (1.f + __expf(-g))) * u;
                } else {
                    int mrow = mbase + ml;
                    if (mrow < ne) {
                        size_t s = (size_t)(oe + mrow);
                        float g = v, u = acc2[i][j][r];
                        C[s * N + n] = (g / (1.f + __expf(-g))) * u;
                    }
                }
            }
        }
    }
}

// ---------------- MFMA flash attention (unchanged from verified Round-9 kernel) ----------------
__global__ __launch_bounds__(256) void attn_mfma_kernel(const float* __restrict__ q,
                                                        const float* __restrict__ k,
                                                        const float* __restrict__ v,
                                                        float* __restrict__ ctx) {
    int qt = blockIdx.x, h = blockIdx.y, b = blockIdx.z;
    int tid = threadIdx.x;
    int lane = tid & 63, wid = tid >> 6;
    int lm = lane & 15, hi = lane >> 4;

    __shared__ short Ks[64 * 64];      // 8 KB, row stride 128 B (swizzled)
    __shared__ short Vt[64 * 64];      // 8 KB, row = d, col = kv (swizzled)
    __shared__ short Ps[4][16 * 64];   // 8 KB, per-wave P tile (swizzled)

    // ---- Q fragments (held for the whole kernel) ----
    int qrow = qt * 64 + wid * 16 + lm;
    const float* qptr = q + ((size_t)(b * TS + qrow)) * TH + h * THD;
    short8 qf[2];
#pragma unroll
    for (int ksl = 0; ksl < 2; ++ksl) {
        const float4* qp = (const float4*)(qptr + ksl * 32 + hi * 8);
        float4 a = qp[0], c = qp[1];
        short8 p;
        p[0] = toBF(a.x); p[1] = toBF(a.y); p[2] = toBF(a.z); p[3] = toBF(a.w);
        p[4] = toBF(c.x); p[5] = toBF(c.y); p[6] = toBF(c.z); p[7] = toBF(c.w);
        qf[ksl] = p;
    }

    f32x4 oacc[4] = {};                 // [nsub] -> O[16 q][64 d]
    float mrun[4] = {-1e30f, -1e30f, -1e30f, -1e30f};
    float lrun[4] = {0.f, 0.f, 0.f, 0.f};

    // staging coords
    int kr = tid >> 2, kc = (tid & 3) * 16;           // K: row, col-base (16 dims)
    const float* ksrc = k + ((size_t)(b * TS + kr)) * TH + h * THD + kc;
    int kv0 = (tid & 31) * 2, vd0 = (tid >> 5) * 8;   // V: kv pair, 8-dim block
    const float* vsrc = v + ((size_t)(b * TS + kv0)) * TH + h * THD + vd0;

    for (int j0 = 0; j0 < TS; j0 += 64) {
        // ---- global loads (K tile row-major, V tile for transpose) ----
        const float4* kp = (const float4*)(ksrc + (size_t)j0 * TH);
        float4 kv4[4] = {kp[0], kp[1], kp[2], kp[3]};
        const float4* vp0 = (const float4*)(vsrc + (size_t)j0 * TH);
        const float4* vp1 = (const float4*)(vsrc + (size_t)(j0 + 1) * TH);
        float4 va0 = vp0[0], va1 = vp0[1];   // V[kv0][vd0..+7]
        float4 vb0 = vp1[0], vb1 = vp1[1];   // V[kv0+1][vd0..+7]
        __syncthreads();   // previous tile's LDS reads complete
        // ---- write Ks (2x short8, swizzled) ----
#pragma unroll
        for (int w = 0; w < 2; ++w) {
            const float* src = (const float*)&kv4[2 * w];
            short8 p;
#pragma unroll
            for (int u = 0; u < 8; ++u) p[u] = toBF(src[u]);
            int off = (kr * 128 + (kc + 8 * w) * 2) ^ ((kr & 7) << 4);
            *(short8*)((char*)Ks + off) = p;
        }
        // ---- write Vt transposed (8x b32, 2 kv packed, swizzled) ----
        {
            const float* a_ = (const float*)&va0;  // kv0   dims vd0..vd0+7
            const float* b_ = (const float*)&vb0;  // kv0+1
#pragma unroll
            for (int i = 0; i < 8; ++i) {
                float fa = (i < 4) ? a_[i] : ((const float*)&va1)[i - 4];
                float fb = (i < 4) ? b_[i] : ((const float*)&vb1)[i - 4];
                int d = vd0 + i;
                unsigned pk = (unsigned)(unsigned short)toBF(fa)
                            | ((unsigned)(unsigned short)toBF(fb) << 16);
                int off = (d * 128 + kv0 * 2) ^ ((d & 7) << 4);
                *(unsigned*)((char*)Vt + off) = pk;
            }
        }
        __syncthreads();
        // ---- QK^T: S[16 q][64 kv] ----
        f32x4 sacc[4] = {};
#pragma unroll
        for (int ksl = 0; ksl < 2; ++ksl) {
#pragma unroll
            for (int jsub = 0; jsub < 4; ++jsub) {
                int rowb = jsub * 16 + lm;
                int off = (rowb * 128 + ksl * 64 + hi * 16) ^ ((rowb & 7) << 4);
                short8 bk = *(const short8*)((const char*)Ks + off);
                sacc[jsub] = __builtin_amdgcn_mfma_f32_16x16x32_bf16(qf[ksl], bk, sacc[jsub], 0, 0, 0);
            }
        }
        // ---- online softmax (scaled domain) ----
#pragma unroll
        for (int jsub = 0; jsub < 4; ++jsub)
#pragma unroll
            for (int r = 0; r < 4; ++r) sacc[jsub][r] *= 0.125f;
#pragma unroll
        for (int r = 0; r < 4; ++r) {
            float tm = fmaxf(fmaxf(sacc[0][r], sacc[1][r]), fmaxf(sacc[2][r], sacc[3][r]));
            tm = fmaxf(tm, __shfl_xor(tm, 1));
            tm = fmaxf(tm, __shfl_xor(tm, 2));
            tm = fmaxf(tm, __shfl_xor(tm, 4));
            tm = fmaxf(tm, __shfl_xor(tm, 8));
            float mnew = fmaxf(mrun[r], tm);
            float corr = __expf(mrun[r] - mnew);
            mrun[r] = mnew;
            float rs = 0.f;
#pragma unroll
            for (int jsub = 0; jsub < 4; ++jsub) {
                float p = __expf(sacc[jsub][r] - mnew);
                sacc[jsub][r] = p;
                rs += p;
            }
            rs += __shfl_xor(rs, 1);
            rs += __shfl_xor(rs, 2);
            rs += __shfl_xor(rs, 4);
            rs += __shfl_xor(rs, 8);
            lrun[r] = lrun[r] * corr + rs;
#pragma unroll
            for (int nsub = 0; nsub < 4; ++nsub) oacc[nsub][r] *= corr;
        }
        // ---- P -> wave-private LDS (D-layout scatter, swizzled) ----
        char* psw = (char*)Ps[wid];
#pragma unroll
        for (int jsub = 0; jsub < 4; ++jsub)
#pragma unroll
            for (int r = 0; r < 4; ++r) {
                int row = hi * 4 + r;
                int col = jsub * 16 + lm;
                int off = (row * 128 + col * 2) ^ ((row & 7) << 4);
                *(short*)(psw + off) = toBF(sacc[jsub][r]);
            }
        // ---- read P as A-frags, PV MFMAs ----
#pragma unroll
        for (int ksl = 0; ksl < 2; ++ksl) {
            int offp = (lm * 128 + ksl * 64 + hi * 16) ^ ((lm & 7) << 4);
            short8 pa = *(const short8*)((const char*)psw + offp);
#pragma unroll
            for (int nsub = 0; nsub < 4; ++nsub) {
                int rowb = nsub * 16 + lm;
                int offv = (rowb * 128 + ksl * 64 + hi * 16) ^ ((rowb & 7) << 4);
                short8 bv = *(const short8*)((const char*)Vt + offv);
                oacc[nsub] = __builtin_amdgcn_mfma_f32_16x16x32_bf16(pa, bv, oacc[nsub], 0, 0, 0);
            }
        }
    }
    // ---- epilogue: O /= l ----
    float inv[4];
#pragma unroll
    for (int r = 0; r < 4; ++r) inv[r] = 1.f / lrun[r];
#pragma unroll
    for (int r = 0; r < 4; ++r) {
        int row = qt * 64 + wid * 16 + hi * 4 + r;
        float* cp = ctx + ((size_t)(b * TS + row)) * TH + h * THD;
#pragma unroll
        for (int nsub = 0; nsub < 4; ++nsub)
            cp[nsub * 16 + lm] = oacc[nsub][r] * inv[r];
    }
}

// ---------------- gate + top2 (NO global atomics — counts done by hist_kernel) ------------
__global__ __launch_bounds__(64) void gate_topk_kernel(const float* __restrict__ xn2,
                                                       const float* __restrict__ gate_w,
                                                       float* __restrict__ tk_w,
                                                       int* __restrict__ tk_e) {
    int t = blockIdx.x;
    int lane = threadIdx.x;
    const float* xr = xn2 + (size_t)t * TH;
    float xv[12];
#pragma unroll
    for (int i = 0; i < 12; ++i) xv[i] = xr[lane + 64 * i];
    __shared__ float logits[TE];
    for (int e = 0; e < TE; ++e) {
        const float* gw = gate_w + (size_t)e * TH;
        float acc = 0.f;
#pragma unroll
        for (int i = 0; i < 12; ++i) acc += xv[i] * gw[lane + 64 * i];
#pragma unroll
        for (int off = 32; off > 0; off >>= 1) acc += __shfl_down(acc, off);
        if (lane == 0) logits[e] = acc;
    }
    __syncthreads();
    if (lane == 0) {
        float mx = -1e30f;
        for (int e = 0; e < TE; ++e) mx = fmaxf(mx, logits[e]);
        float ex[TE];
        float sum = 0.f;
        for (int e = 0; e < TE; ++e) { ex[e] = __expf(logits[e] - mx); sum += ex[e]; }
        int e0 = 0; float p0 = -1.f;
        for (int e = 0; e < TE; ++e) if (ex[e] > p0) { p0 = ex[e]; e0 = e; }
        int e1 = -1; float p1 = -1.f;
        for (int e = 0; e < TE; ++e) if (e != e0 && ex[e] > p1) { p1 = ex[e]; e1 = e; }
        float w0 = p0 / sum, w1 = p1 / sum;
        float denom = w0 + w1 + 1e-20f;
        tk_e[2 * t] = e0; tk_e[2 * t + 1] = e1;
        tk_w[2 * t] = w0 / denom; tk_w[2 * t + 1] = w1 / denom;
    }
}

// ---------------- histogram: LDS per-block counts, 8 global atomics per block -------------
__global__ __launch_bounds__(256) void hist_kernel(const int* __restrict__ tk_e,
                                                   int* __restrict__ counts) {
    __shared__ int hc[TE];
    int tid = threadIdx.x;
    if (tid < TE) hc[tid] = 0;
    __syncthreads();
    int t = blockIdx.x * 256 + tid;
    atomicAdd(&hc[tk_e[2 * t]], 1);
    atomicAdd(&hc[tk_e[2 * t + 1]], 1);
    __syncthreads();
    if (tid < TE) atomicAdd(&counts[tid], hc[tid]);
}

__global__ void scan_kernel(const int* __restrict__ counts, int* __restrict__ offsets,
                            int* __restrict__ fill) {
    if (threadIdx.x == 0) {
        int run = 0;
        for (int e = 0; e < TE; ++e) { offsets[e] = run; fill[e] = run; run += counts[e]; }
    }
}

// ---------------- scatter: two-level counting sort (LDS rank + 8 global atomics/block) ----
// Order within each expert bucket is permuted vs the single-atomic version, but all
// consumers (bucket_tok/bucket_w gather, slot_of indirection) are order-independent.
__global__ __launch_bounds__(256) void scatter_kernel(const int* __restrict__ tk_e,
                                                      const float* __restrict__ tk_w,
                                                      int* __restrict__ fill,
                                                      int* __restrict__ bucket_tok,
                                                      float* __restrict__ bucket_w,
                                                      int* __restrict__ slot_of) {
    __shared__ int hc[TE];
    __shared__ int base[TE];
    int tid = threadIdx.x;
    if (tid < TE) hc[tid] = 0;
    __syncthreads();
    int t = blockIdx.x * 256 + tid;
    int e0 = tk_e[2 * t], e1 = tk_e[2 * t + 1];
    int r0 = atomicAdd(&hc[e0], 1);   // LDS atomic: local rank
    int r1 = atomicAdd(&hc[e1], 1);
    __syncthreads();
    if (tid < TE) base[tid] = atomicAdd(&fill[tid], hc[tid]);  // reserve block range
    __syncthreads();
    int p0 = base[e0] + r0, p1 = base[e1] + r1;
    bucket_tok[p0] = t; bucket_w[p0] = tk_w[2 * t];     slot_of[2 * t]     = p0;
    bucket_tok[p1] = t; bucket_w[p1] = tk_w[2 * t + 1]; slot_of[2 * t + 1] = p1;
}

extern "C" void kernel_launch(void* const* d_in, const int* in_sizes, int n_in,
                              void* d_out, int out_size, void* d_ws, size_t ws_size,
                              hipStream_t stream) {
    const float* hidden  = (const float*)d_in[0];
    const float* norm1_w = (const float*)d_in[1];
    const float* Wq      = (const float*)d_in[2];
    const float* Wk      = (const float*)d_in[3];
    const float* Wv      = (const float*)d_in[4];
    const float* Wo      = (const float*)d_in[5];
    const float* norm2_w = (const float*)d_in[6];
    const float* gate_w  = (const float*)d_in[7];
    const float* Weg     = (const float*)d_in[8];
    const float* Weu     = (const float*)d_in[9];
    const float* Wed     = (const float*)d_in[10];
    const float* Wsg     = (const float*)d_in[11];
    const float* Wsu     = (const float*)d_in[12];
    const float* Wsd     = (const float*)d_in[13];
    float* out = (float*)d_out;

    const size_t BUF = (size_t)TT * TH;  // 3,145,728 floats
    float* ws  = (float*)d_ws;
    float* xn1  = ws;             // buf0
    float* qb   = ws + 1 * BUF;   // buf1; later act (TT*TKK*TF == BUF)
    float* kb   = ws + 2 * BUF;   // buf2; later yslot (spans buf2+buf3)
    float* vb   = ws + 3 * BUF;   // buf3
    float* ctxb = ws + 4 * BUF;   // buf4; later sact
    float* xn2  = ws + 5 * BUF;   // buf5
    char* tail = (char*)(ws + 6 * BUF);
    int*   tk_e       = (int*)tail;
    float* tk_w       = (float*)(tail + (size_t)TT * 2 * 4);
    int*   slot_of    = (int*)(tail + (size_t)TT * 2 * 8);
    int*   bucket_tok = (int*)(tail + (size_t)TT * 2 * 12);
    float* bucket_w   = (float*)(tail + (size_t)TT * 2 * 16);
    int*   counts     = (int*)(tail + (size_t)TT * 2 * 20);
    int*   offsets    = counts + 8;
    int*   fill       = counts + 16;

    float* act   = qb;
    float* yslot = kb;
    float* sact  = ctxb;

    hipMemsetAsync(counts, 0, 8 * sizeof(int), stream);

    rmsnorm_kernel<<<TT, 256, 0, stream>>>(hidden, norm1_w, xn1);

    // QKV: M=4096, N=768, K=768
    dim3 g1(TH / 128, TT / 128);
    mfma_gemm_kernel<0><<<g1, 256, 0, stream>>>(xn1, Wq, nullptr, qb, nullptr,
        nullptr, nullptr, nullptr, nullptr, nullptr, nullptr, TH, TH);
    mfma_gemm_kernel<0><<<g1, 256, 0, stream>>>(xn1, Wk, nullptr, kb, nullptr,
        nullptr, nullptr, nullptr, nullptr, nullptr, nullptr, TH, TH);
    mfma_gemm_kernel<0><<<g1, 256, 0, stream>>>(xn1, Wv, nullptr, vb, nullptr,
        nullptr, nullptr, nullptr, nullptr, nullptr, nullptr, TH, TH);

    dim3 ga(TS / 64, TNH, TB);
    attn_mfma_kernel<<<ga, 256, 0, stream>>>(qb, kb, vb, ctxb);

    // Wo + residual
    mfma_gemm_kernel<1><<<g1, 256, 0, stream>>>(ctxb, Wo, nullptr, out, hidden,
        nullptr, nullptr, nullptr, nullptr, nullptr, nullptr, TH, TH);

    rmsnorm_kernel<<<TT, 256, 0, stream>>>(out, norm2_w, xn2);

    gate_topk_kernel<<<TT, 64, 0, stream>>>(xn2, gate_w, tk_w, tk_e);
    hist_kernel<<<TT / 256, 256, 0, stream>>>(tk_e, counts);
    scan_kernel<<<1, 64, 0, stream>>>(counts, offsets, fill);
    scatter_kernel<<<TT / 256, 256, 0, stream>>>(tk_e, tk_w, fill, bucket_tok, bucket_w, slot_of);

    // MoE up: dual-B + gather + SwiGLU. N=384, K=768
    mfma_gemm_kernel<5><<<dim3(TF / 64, TT * TKK / 128, TE), 256, 0, stream>>>(
        xn2, Weg, Weu, act, nullptr,
        bucket_tok, offsets, counts, nullptr, nullptr, nullptr, TF, TH);
    // MoE down: per-slot scale. N=768, K=384
    mfma_gemm_kernel<2><<<dim3(TH / 128, TT * TKK / 128, TE), 256, 0, stream>>>(
        act, Wed, nullptr, yslot, nullptr,
        nullptr, offsets, counts, bucket_w, nullptr, nullptr, TH, TF);

    // shared expert up: dual-B SwiGLU. N=768(SF), K=768
    mfma_gemm_kernel<4><<<dim3(TSF / 64, TT / 128), 256, 0, stream>>>(
        xn2, Wsg, Wsu, sact, nullptr,
        nullptr, nullptr, nullptr, nullptr, nullptr, nullptr, TSF, TH);
    // final: out += sact@Wsd^T + yslot[s0] + yslot[s1]. N=768, K=768
    mfma_gemm_kernel<3><<<dim3(TH / 128, TT / 128), 256, 0, stream>>>(
        sact, Wsd, nullptr, out, nullptr,
        nullptr, nullptr, nullptr, nullptr, yslot, slot_of, TH, TSF);
}

// Round 13
// 499.664 us; speedup vs baseline: 4.4043x; 1.0441x over previous
//
#include <hip/hip_runtime.h>
#include <hip/hip_bf16.h>

#define TB 4
#define TS 1024
#define TH 768
#define TNH 12
#define THD 64
#define TE 8
#define TKK 2
#define TF 384
#define TSF 768
#define TT (TB*TS)
#define REPS 1e-6f

typedef __attribute__((ext_vector_type(8))) short short8;   // 8 bf16 = 4 VGPRs (MFMA A/B frag)
typedef __attribute__((ext_vector_type(4))) float f32x4;    // MFMA C/D frag

__device__ inline short toBF(float f) {
    __hip_bfloat16 h = __float2bfloat16(f);
    return *reinterpret_cast<short*>(&h);
}

// ---------------- RMSNorm: one block per token ----------------
__global__ __launch_bounds__(256) void rmsnorm_kernel(const float* __restrict__ x,
                                                      const float* __restrict__ w,
                                                      float* __restrict__ out) {
    int t = blockIdx.x;
    int tid = threadIdx.x;
    const float* xr = x + (size_t)t * TH;
    float v0 = xr[tid], v1 = xr[tid + 256], v2 = xr[tid + 512];
    float ss = v0 * v0 + v1 * v1 + v2 * v2;
    __shared__ float red[256];
    red[tid] = ss;
    __syncthreads();
    for (int s = 128; s > 0; s >>= 1) {
        if (tid < s) red[tid] += red[tid + s];
        __syncthreads();
    }
    float scale = rsqrtf(red[0] / (float)TH + REPS);
    float* o = out + (size_t)t * TH;
    o[tid]       = w[tid] * v0 * scale;
    o[tid + 256] = w[tid + 256] * v1 * scale;
    o[tid + 512] = w[tid + 512] * v2 * scale;
}

// ---------------- MFMA GEMM-BT ----------
// EPI 0: plain fp32 store                    EPI 1: + res
// EPI 2: expert rows, *bucket_w[slot]        EPI 3: C += acc + yslot[s0] + yslot[s1]
// EPI 4: dual-B silu(g)*u                    EPI 5: dual-B silu(g)*u, gathered A rows
// EPI 6: plain BF16 store (ushort* C)        <- QKV for bf16 attention
template <int EPI>
__global__ __launch_bounds__(256) void mfma_gemm_kernel(
    const float* __restrict__ A, const float* __restrict__ B1, const float* __restrict__ B2,
    float* __restrict__ C, const float* __restrict__ res,
    const int* __restrict__ rowmap, const int* __restrict__ offsets,
    const int* __restrict__ counts, const float* __restrict__ bucket_w,
    const float* __restrict__ yslot, const int* __restrict__ slot_of,
    int N, int K)
{
    constexpr bool DUAL = (EPI == 4 || EPI == 5);
    constexpr bool EXPERT = (EPI == 2 || EPI == 5);
    constexpr int BN = DUAL ? 64 : 128;
    constexpr int NJ = DUAL ? 2 : 4;

    __shared__ short As[128][40];
    __shared__ short Bs1[BN][40];
    __shared__ short Bs2[DUAL ? BN : 1][40];

    int tid = threadIdx.x;
    int e = blockIdx.z;
    int ne = 0x7fffffff, oe = 0;
    if (EXPERT) { ne = counts[e]; oe = offsets[e]; }
    int mbase = blockIdx.y * 128;
    if (EXPERT && mbase >= ne) return;
    int n0 = blockIdx.x * BN;

    int sr = tid >> 1;
    int sh = tid & 1;
    size_t arow = 0; bool avalid = true;
    if (EPI == 5) {
        int mrow = mbase + sr;
        int tok = (mrow < ne) ? rowmap[oe + mrow] : -1;
        avalid = tok >= 0; arow = (tok >= 0) ? (size_t)tok : 0;
    } else if (EPI == 2) {
        int mrow = mbase + sr;
        avalid = mrow < ne; arow = (size_t)(oe + mrow);
    } else {
        arow = (size_t)(mbase + sr);
    }
    const float* asrc = A + arow * K + sh * 16;
    size_t bOff = (size_t)e * (size_t)N * K;
    const float* b1src = B1 + bOff + (size_t)(n0 + sr) * K + sh * 16;
    const float* b2src = DUAL ? (B2 + bOff + (size_t)(n0 + sr) * K + sh * 16) : nullptr;
    bool bstage = (sr < BN);

    int lane = tid & 63, wid = tid >> 6;
    int wr = wid >> 1, wc = wid & 1;
    int lm = lane & 15, lk = (lane >> 4) * 8;

    f32x4 acc[4][NJ] = {};
    f32x4 acc2[DUAL ? 4 : 1][NJ] = {};

    for (int k0 = 0; k0 < K; k0 += 32) {
        float4 av[4] = {};
        float4 bv[4] = {};
        float4 bv2[4] = {};
        if (avalid) {
            const float4* ap = (const float4*)(asrc + k0);
            av[0] = ap[0]; av[1] = ap[1]; av[2] = ap[2]; av[3] = ap[3];
        }
        if (bstage) {
            const float4* bp = (const float4*)(b1src + k0);
            bv[0] = bp[0]; bv[1] = bp[1]; bv[2] = bp[2]; bv[3] = bp[3];
            if (DUAL) {
                const float4* bp2 = (const float4*)(b2src + k0);
                bv2[0] = bp2[0]; bv2[1] = bp2[1]; bv2[2] = bp2[2]; bv2[3] = bp2[3];
            }
        }
        __syncthreads();
        {
            const float* af_ = (const float*)av;
            short8 p0, p1;
#pragma unroll
            for (int u = 0; u < 8; ++u) p0[u] = toBF(af_[u]);
#pragma unroll
            for (int u = 0; u < 8; ++u) p1[u] = toBF(af_[8 + u]);
            *(short8*)&As[sr][sh * 16]     = p0;
            *(short8*)&As[sr][sh * 16 + 8] = p1;
        }
        if (bstage) {
            const float* bf_ = (const float*)bv;
            short8 p0, p1;
#pragma unroll
            for (int u = 0; u < 8; ++u) p0[u] = toBF(bf_[u]);
#pragma unroll
            for (int u = 0; u < 8; ++u) p1[u] = toBF(bf_[8 + u]);
            *(short8*)&Bs1[sr][sh * 16]     = p0;
            *(short8*)&Bs1[sr][sh * 16 + 8] = p1;
            if (DUAL) {
                const float* b2_ = (const float*)bv2;
                short8 q0, q1;
#pragma unroll
                for (int u = 0; u < 8; ++u) q0[u] = toBF(b2_[u]);
#pragma unroll
                for (int u = 0; u < 8; ++u) q1[u] = toBF(b2_[8 + u]);
                *(short8*)&Bs2[sr][sh * 16]     = q0;
                *(short8*)&Bs2[sr][sh * 16 + 8] = q1;
            }
        }
        __syncthreads();
        short8 af[4], bf1[NJ], bf2[NJ];
#pragma unroll
        for (int i = 0; i < 4; ++i) af[i] = *(const short8*)&As[wr * 64 + i * 16 + lm][lk];
#pragma unroll
        for (int j = 0; j < NJ; ++j) {
            bf1[j] = *(const short8*)&Bs1[wc * (BN / 2) + j * 16 + lm][lk];
            if (DUAL) bf2[j] = *(const short8*)&Bs2[wc * (BN / 2) + j * 16 + lm][lk];
        }
#pragma unroll
        for (int i = 0; i < 4; ++i)
#pragma unroll
            for (int j = 0; j < NJ; ++j) {
                acc[i][j] = __builtin_amdgcn_mfma_f32_16x16x32_bf16(af[i], bf1[j], acc[i][j], 0, 0, 0);
                if (DUAL)
                    acc2[i][j] = __builtin_amdgcn_mfma_f32_16x16x32_bf16(af[i], bf2[j], acc2[i][j], 0, 0, 0);
            }
    }

#pragma unroll
    for (int i = 0; i < 4; ++i) {
#pragma unroll
        for (int j = 0; j < NJ; ++j) {
            int mloc0 = wr * 64 + i * 16 + (lane >> 4) * 4;
            int n = n0 + wc * (BN / 2) + j * 16 + lm;
#pragma unroll
            for (int r = 0; r < 4; ++r) {
                int ml = mloc0 + r;
                float v = acc[i][j][r];
                if (EPI == 0) {
                    size_t m = (size_t)(mbase + ml);
                    C[m * N + n] = v;
                } else if (EPI == 6) {
                    size_t m = (size_t)(mbase + ml);
                    ((unsigned short*)C)[m * N + n] = (unsigned short)toBF(v);
                } else if (EPI == 1) {
                    size_t m = (size_t)(mbase + ml);
                    C[m * N + n] = v + res[m * N + n];
                } else if (EPI == 2) {
                    int mrow = mbase + ml;
                    if (mrow < ne) {
                        size_t s = (size_t)(oe + mrow);
                        C[s * N + n] = bucket_w[s] * v;
                    }
                } else if (EPI == 3) {
                    size_t m = (size_t)(mbase + ml);
                    int s0 = slot_of[2 * m], s1 = slot_of[2 * m + 1];
                    C[m * N + n] += v + yslot[(size_t)s0 * N + n] + yslot[(size_t)s1 * N + n];
                } else if (EPI == 4) {
                    size_t m = (size_t)(mbase + ml);
                    float g = v, u = acc2[i][j][r];
                    C[m * N + n] = (g / (1.f + __expf(-g))) * u;
                } else {
                    int mrow = mbase + ml;
                    if (mrow < ne) {
                        size_t s = (size_t)(oe + mrow);
                        float g = v, u = acc2[i][j][r];
                        C[s * N + n] = (g / (1.f + __expf(-g))) * u;
                    }
                }
            }
        }
    }
}

// ---------------- MFMA flash attention, BF16 Q/K/V inputs ----------------
// Same structure as verified Round-11 kernel; staging is now pure copy/pack
// (no float->bf16 conversion) and global bytes are halved.
__global__ __launch_bounds__(256) void attn_mfma_kernel(const unsigned short* __restrict__ q,
                                                        const unsigned short* __restrict__ k,
                                                        const unsigned short* __restrict__ v,
                                                        float* __restrict__ ctx) {
    int qt = blockIdx.x, h = blockIdx.y, b = blockIdx.z;
    int tid = threadIdx.x;
    int lane = tid & 63, wid = tid >> 6;
    int lm = lane & 15, hi = lane >> 4;

    __shared__ short Ks[64 * 64];      // 8 KB, row stride 128 B (swizzled)
    __shared__ short Vt[64 * 64];      // 8 KB, row = d, col = kv (swizzled)
    __shared__ short Ps[4][16 * 64];   // 8 KB, per-wave P tile (swizzled)

    // ---- Q fragments: direct bf16 loads ----
    int qrow = qt * 64 + wid * 16 + lm;
    const unsigned short* qptr = q + ((size_t)(b * TS + qrow)) * TH + h * THD;
    short8 qf[2];
#pragma unroll
    for (int ksl = 0; ksl < 2; ++ksl)
        qf[ksl] = *(const short8*)(qptr + ksl * 32 + hi * 8);

    f32x4 oacc[4] = {};                 // [nsub] -> O[16 q][64 d]
    float mrun[4] = {-1e30f, -1e30f, -1e30f, -1e30f};
    float lrun[4] = {0.f, 0.f, 0.f, 0.f};

    // staging coords
    int kr = tid >> 2, kc = (tid & 3) * 16;           // K: row, col-base (16 dims)
    const unsigned short* ksrc = k + ((size_t)(b * TS + kr)) * TH + h * THD + kc;
    int kv0 = (tid & 31) * 2, vd0 = (tid >> 5) * 8;   // V: kv pair, 8-dim block
    const unsigned short* vsrc = v + ((size_t)(b * TS + kv0)) * TH + h * THD + vd0;

    for (int j0 = 0; j0 < TS; j0 += 64) {
        // ---- global loads (bf16, no conversion) ----
        short8 k8a = *(const short8*)(ksrc + (size_t)j0 * TH);
        short8 k8b = *(const short8*)(ksrc + (size_t)j0 * TH + 8);
        short8 v8a = *(const short8*)(vsrc + (size_t)j0 * TH);          // V[kv0][vd0..+7]
        short8 v8b = *(const short8*)(vsrc + (size_t)(j0 + 1) * TH);    // V[kv0+1][vd0..+7]
        __syncthreads();   // previous tile's LDS reads complete
        // ---- write Ks (2x short8, swizzled) ----
        {
            int off0 = (kr * 128 + kc * 2) ^ ((kr & 7) << 4);
            int off1 = (kr * 128 + (kc + 8) * 2) ^ ((kr & 7) << 4);
            *(short8*)((char*)Ks + off0) = k8a;
            *(short8*)((char*)Ks + off1) = k8b;
        }
        // ---- write Vt transposed (8x b32, 2 kv packed, swizzled) ----
#pragma unroll
        for (int i = 0; i < 8; ++i) {
            int d = vd0 + i;
            unsigned pk = (unsigned)(unsigned short)v8a[i]
                        | ((unsigned)(unsigned short)v8b[i] << 16);
            int off = (d * 128 + kv0 * 2) ^ ((d & 7) << 4);
            *(unsigned*)((char*)Vt + off) = pk;
        }
        __syncthreads();
        // ---- QK^T: S[16 q][64 kv] ----
        f32x4 sacc[4] = {};
#pragma unroll
        for (int ksl = 0; ksl < 2; ++ksl) {
#pragma unroll
            for (int jsub = 0; jsub < 4; ++jsub) {
                int rowb = jsub * 16 + lm;
                int off = (rowb * 128 + ksl * 64 + hi * 16) ^ ((rowb & 7) << 4);
                short8 bk = *(const short8*)((const char*)Ks + off);
                sacc[jsub] = __builtin_amdgcn_mfma_f32_16x16x32_bf16(qf[ksl], bk, sacc[jsub], 0, 0, 0);
            }
        }
        // ---- online softmax (scaled domain) ----
#pragma unroll
        for (int jsub = 0; jsub < 4; ++jsub)
#pragma unroll
            for (int r = 0; r < 4; ++r) sacc[jsub][r] *= 0.125f;
#pragma unroll
        for (int r = 0; r < 4; ++r) {
            float tm = fmaxf(fmaxf(sacc[0][r], sacc[1][r]), fmaxf(sacc[2][r], sacc[3][r]));
            tm = fmaxf(tm, __shfl_xor(tm, 1));
            tm = fmaxf(tm, __shfl_xor(tm, 2));
            tm = fmaxf(tm, __shfl_xor(tm, 4));
            tm = fmaxf(tm, __shfl_xor(tm, 8));
            float mnew = fmaxf(mrun[r], tm);
            float corr = __expf(mrun[r] - mnew);
            mrun[r] = mnew;
            float rs = 0.f;
#pragma unroll
            for (int jsub = 0; jsub < 4; ++jsub) {
                float p = __expf(sacc[jsub][r] - mnew);
                sacc[jsub][r] = p;
                rs += p;
            }
            rs += __shfl_xor(rs, 1);
            rs += __shfl_xor(rs, 2);
            rs += __shfl_xor(rs, 4);
            rs += __shfl_xor(rs, 8);
            lrun[r] = lrun[r] * corr + rs;
#pragma unroll
            for (int nsub = 0; nsub < 4; ++nsub) oacc[nsub][r] *= corr;
        }
        // ---- P -> wave-private LDS (D-layout scatter, swizzled) ----
        char* psw = (char*)Ps[wid];
#pragma unroll
        for (int jsub = 0; jsub < 4; ++jsub)
#pragma unroll
            for (int r = 0; r < 4; ++r) {
                int row = hi * 4 + r;
                int col = jsub * 16 + lm;
                int off = (row * 128 + col * 2) ^ ((row & 7) << 4);
                *(short*)(psw + off) = toBF(sacc[jsub][r]);
            }
        // ---- read P as A-frags, PV MFMAs ----
#pragma unroll
        for (int ksl = 0; ksl < 2; ++ksl) {
            int offp = (lm * 128 + ksl * 64 + hi * 16) ^ ((lm & 7) << 4);
            short8 pa = *(const short8*)((const char*)psw + offp);
#pragma unroll
            for (int nsub = 0; nsub < 4; ++nsub) {
                int rowb = nsub * 16 + lm;
                int offv = (rowb * 128 + ksl * 64 + hi * 16) ^ ((rowb & 7) << 4);
                short8 bv = *(const short8*)((const char*)Vt + offv);
                oacc[nsub] = __builtin_amdgcn_mfma_f32_16x16x32_bf16(pa, bv, oacc[nsub], 0, 0, 0);
            }
        }
    }
    // ---- epilogue: O /= l ----
    float inv[4];
#pragma unroll
    for (int r = 0; r < 4; ++r) inv[r] = 1.f / lrun[r];
#pragma unroll
    for (int r = 0; r < 4; ++r) {
        int row = qt * 64 + wid * 16 + hi * 4 + r;
        float* cp = ctx + ((size_t)(b * TS + row)) * TH + h * THD;
#pragma unroll
        for (int nsub = 0; nsub < 4; ++nsub)
            cp[nsub * 16 + lm] = oacc[nsub][r] * inv[r];
    }
}

// ---------------- gate + top2 (NO global atomics — counts done by hist_kernel) ------------
__global__ __launch_bounds__(64) void gate_topk_kernel(const float* __restrict__ xn2,
                                                       const float* __restrict__ gate_w,
                                                       float* __restrict__ tk_w,
                                                       int* __restrict__ tk_e) {
    int t = blockIdx.x;
    int lane = threadIdx.x;
    const float* xr = xn2 + (size_t)t * TH;
    float xv[12];
#pragma unroll
    for (int i = 0; i < 12; ++i) xv[i] = xr[lane + 64 * i];
    __shared__ float logits[TE];
    for (int e = 0; e < TE; ++e) {
        const float* gw = gate_w + (size_t)e * TH;
        float acc = 0.f;
#pragma unroll
        for (int i = 0; i < 12; ++i) acc += xv[i] * gw[lane + 64 * i];
#pragma unroll
        for (int off = 32; off > 0; off >>= 1) acc += __shfl_down(acc, off);
        if (lane == 0) logits[e] = acc;
    }
    __syncthreads();
    if (lane == 0) {
        float mx = -1e30f;
        for (int e = 0; e < TE; ++e) mx = fmaxf(mx, logits[e]);
        float ex[TE];
        float sum = 0.f;
        for (int e = 0; e < TE; ++e) { ex[e] = __expf(logits[e] - mx); sum += ex[e]; }
        int e0 = 0; float p0 = -1.f;
        for (int e = 0; e < TE; ++e) if (ex[e] > p0) { p0 = ex[e]; e0 = e; }
        int e1 = -1; float p1 = -1.f;
        for (int e = 0; e < TE; ++e) if (e != e0 && ex[e] > p1) { p1 = ex[e]; e1 = e; }
        float w0 = p0 / sum, w1 = p1 / sum;
        float denom = w0 + w1 + 1e-20f;
        tk_e[2 * t] = e0; tk_e[2 * t + 1] = e1;
        tk_w[2 * t] = w0 / denom; tk_w[2 * t + 1] = w1 / denom;
    }
}

// ---------------- histogram: LDS per-block counts, 8 global atomics per block -------------
__global__ __launch_bounds__(256) void hist_kernel(const int* __restrict__ tk_e,
                                                   int* __restrict__ counts) {
    __shared__ int hc[TE];
    int tid = threadIdx.x;
    if (tid < TE) hc[tid] = 0;
    __syncthreads();
    int t = blockIdx.x * 256 + tid;
    atomicAdd(&hc[tk_e[2 * t]], 1);
    atomicAdd(&hc[tk_e[2 * t + 1]], 1);
    __syncthreads();
    if (tid < TE) atomicAdd(&counts[tid], hc[tid]);
}

__global__ void scan_kernel(const int* __restrict__ counts, int* __restrict__ offsets,
                            int* __restrict__ fill) {
    if (threadIdx.x == 0) {
        int run = 0;
        for (int e = 0; e < TE; ++e) { offsets[e] = run; fill[e] = run; run += counts[e]; }
    }
}

// ---------------- scatter: two-level counting sort (LDS rank + 8 global atomics/block) ----
__global__ __launch_bounds__(256) void scatter_kernel(const int* __restrict__ tk_e,
                                                      const float* __restrict__ tk_w,
                                                      int* __restrict__ fill,
                                                      int* __restrict__ bucket_tok,
                                                      float* __restrict__ bucket_w,
                                                      int* __restrict__ slot_of) {
    __shared__ int hc[TE];
    __shared__ int base[TE];
    int tid = threadIdx.x;
    if (tid < TE) hc[tid] = 0;
    __syncthreads();
    int t = blockIdx.x * 256 + tid;
    int e0 = tk_e[2 * t], e1 = tk_e[2 * t + 1];
    int r0 = atomicAdd(&hc[e0], 1);   // LDS atomic: local rank
    int r1 = atomicAdd(&hc[e1], 1);
    __syncthreads();
    if (tid < TE) base[tid] = atomicAdd(&fill[tid], hc[tid]);  // reserve block range
    __syncthreads();
    int p0 = base[e0] + r0, p1 = base[e1] + r1;
    bucket_tok[p0] = t; bucket_w[p0] = tk_w[2 * t];     slot_of[2 * t]     = p0;
    bucket_tok[p1] = t; bucket_w[p1] = tk_w[2 * t + 1]; slot_of[2 * t + 1] = p1;
}

extern "C" void kernel_launch(void* const* d_in, const int* in_sizes, int n_in,
                              void* d_out, int out_size, void* d_ws, size_t ws_size,
                              hipStream_t stream) {
    const float* hidden  = (const float*)d_in[0];
    const float* norm1_w = (const float*)d_in[1];
    const float* Wq      = (const float*)d_in[2];
    const float* Wk      = (const float*)d_in[3];
    const float* Wv      = (const float*)d_in[4];
    const float* Wo      = (const float*)d_in[5];
    const float* norm2_w = (const float*)d_in[6];
    const float* gate_w  = (const float*)d_in[7];
    const float* Weg     = (const float*)d_in[8];
    const float* Weu     = (const float*)d_in[9];
    const float* Wed     = (const float*)d_in[10];
    const float* Wsg     = (const float*)d_in[11];
    const float* Wsu     = (const float*)d_in[12];
    const float* Wsd     = (const float*)d_in[13];
    float* out = (float*)d_out;

    const size_t BUF = (size_t)TT * TH;  // 3,145,728 floats
    float* ws  = (float*)d_ws;
    float* xn1  = ws;             // buf0
    float* qb   = ws + 1 * BUF;   // buf1 (bf16 Q uses half); later act (fp32)
    float* kb   = ws + 2 * BUF;   // buf2 (bf16 K); later yslot (spans buf2+buf3)
    float* vb   = ws + 3 * BUF;   // buf3 (bf16 V)
    float* ctxb = ws + 4 * BUF;   // buf4; later sact
    float* xn2  = ws + 5 * BUF;   // buf5
    char* tail = (char*)(ws + 6 * BUF);
    int*   tk_e       = (int*)tail;
    float* tk_w       = (float*)(tail + (size_t)TT * 2 * 4);
    int*   slot_of    = (int*)(tail + (size_t)TT * 2 * 8);
    int*   bucket_tok = (int*)(tail + (size_t)TT * 2 * 12);
    float* bucket_w   = (float*)(tail + (size_t)TT * 2 * 16);
    int*   counts     = (int*)(tail + (size_t)TT * 2 * 20);
    int*   offsets    = counts + 8;
    int*   fill       = counts + 16;

    float* act   = qb;
    float* yslot = kb;
    float* sact  = ctxb;

    hipMemsetAsync(counts, 0, 8 * sizeof(int), stream);

    rmsnorm_kernel<<<TT, 256, 0, stream>>>(hidden, norm1_w, xn1);

    // QKV: M=4096, N=768, K=768 -> BF16 outputs (EPI 6)
    dim3 g1(TH / 128, TT / 128);
    mfma_gemm_kernel<6><<<g1, 256, 0, stream>>>(xn1, Wq, nullptr, qb, nullptr,
        nullptr, nullptr, nullptr, nullptr, nullptr, nullptr, TH, TH);
    mfma_gemm_kernel<6><<<g1, 256, 0, stream>>>(xn1, Wk, nullptr, kb, nullptr,
        nullptr, nullptr, nullptr, nullptr, nullptr, nullptr, TH, TH);
    mfma_gemm_kernel<6><<<g1, 256, 0, stream>>>(xn1, Wv, nullptr, vb, nullptr,
        nullptr, nullptr, nullptr, nullptr, nullptr, nullptr, TH, TH);

    dim3 ga(TS / 64, TNH, TB);
    attn_mfma_kernel<<<ga, 256, 0, stream>>>((const unsigned short*)qb,
                                             (const unsigned short*)kb,
                                             (const unsigned short*)vb, ctxb);

    // Wo + residual
    mfma_gemm_kernel<1><<<g1, 256, 0, stream>>>(ctxb, Wo, nullptr, out, hidden,
        nullptr, nullptr, nullptr, nullptr, nullptr, nullptr, TH, TH);

    rmsnorm_kernel<<<TT, 256, 0, stream>>>(out, norm2_w, xn2);

    gate_topk_kernel<<<TT, 64, 0, stream>>>(xn2, gate_w, tk_w, tk_e);
    hist_kernel<<<TT / 256, 256, 0, stream>>>(tk_e, counts);
    scan_kernel<<<1, 64, 0, stream>>>(counts, offsets, fill);
    scatter_kernel<<<TT / 256, 256, 0, stream>>>(tk_e, tk_w, fill, bucket_tok, bucket_w, slot_of);

    // MoE up: dual-B + gather + SwiGLU. N=384, K=768
    mfma_gemm_kernel<5><<<dim3(TF / 64, TT * TKK / 128, TE), 256, 0, stream>>>(
        xn2, Weg, Weu, act, nullptr,
        bucket_tok, offsets, counts, nullptr, nullptr, nullptr, TF, TH);
    // MoE down: per-slot scale. N=768, K=384
    mfma_gemm_kernel<2><<<dim3(TH / 128, TT * TKK / 128, TE), 256, 0, stream>>>(
        act, Wed, nullptr, yslot, nullptr,
        nullptr, offsets, counts, bucket_w, nullptr, nullptr, TH, TF);

    // shared expert up: dual-B SwiGLU. N=768(SF), K=768
    mfma_gemm_kernel<4><<<dim3(TSF / 64, TT / 128), 256, 0, stream>>>(
        xn2, Wsg, Wsu, sact, nullptr,
        nullptr, nullptr, nullptr, nullptr, nullptr, nullptr, TSF, TH);
    // final: out += sact@Wsd^T + yslot[s0] + yslot[s1]. N=768, K=768
    mfma_gemm_kernel<3><<<dim3(TH / 128, TT / 128), 256, 0, stream>>>(
        sact, Wsd, nullptr, out, nullptr,
        nullptr, nullptr, nullptr, nullptr, yslot, slot_of, TH, TSF);
}